// Round 18
// baseline (375.542 us; speedup 1.0000x reference)
//
#include <hip/hip_runtime.h>
#include <hip/hip_bf16.h>

// QKV upsampling pipeline.
// R17 (resubmit after infra failure): einsum v11 -- vs LDS staging DELETED
// (was the saturated-LDS-pipe majority); phase B loads v directly from
// L2-resident vraw. LDS keeps only qkvs+wsum (7.2KB). Rest = R16 (278us).

constexpr int VOX = 32 * 32 * 32;
constexpr float INV_VOX = 1.0f / 32768.0f;
constexpr float EPSF = 1e-5f;

typedef __attribute__((ext_vector_type(8))) short s16x8;
typedef __attribute__((ext_vector_type(4))) float f32x4;

static __device__ __forceinline__ ushort bf16_bits(float v) {
  __hip_bfloat16 h = __float2bfloat16(v);
  return *reinterpret_cast<ushort*>(&h);
}

// ---------------------------------------------------------------------------
// Merged x-transpose (blocks 0-511) + weight prepack (blocks 512-671).
// ---------------------------------------------------------------------------
__global__ __launch_bounds__(256) void prep_all_kernel(
    const float* __restrict__ x,
    const float* __restrict__ vw,
    const float* __restrict__ q1w, const float* __restrict__ q1b,
    const float* __restrict__ k1w, const float* __restrict__ k1b,
    const float* __restrict__ q2w, const float* __restrict__ q2b,
    const float* __restrict__ k2w, const float* __restrict__ k2b,
    ushort* __restrict__ xh, ushort* __restrict__ xl,
    ushort* __restrict__ wfh, ushort* __restrict__ wfl,
    ushort* __restrict__ wqh, ushort* __restrict__ wql, float* __restrict__ bqk,
    ushort* __restrict__ w2h, ushort* __restrict__ w2l, float* __restrict__ b96)
{
  __shared__ float ts[64][65];
  const int t = threadIdx.x;
  if ((int)blockIdx.x < 512) {
    const int vox0 = blockIdx.x * 64;
#pragma unroll
    for (int i = 0; i < 16; ++i) {
      int e = i * 256 + t;
      int ci = e >> 6, vl = e & 63;
      ts[ci][vl] = x[(size_t)ci * VOX + vox0 + vl];
    }
    __syncthreads();
    const int vl = t >> 2, cig = t & 3;
    uint h[8], l[8];
#pragma unroll
    for (int p = 0; p < 8; ++p) {
      float v0 = ts[cig * 16 + 2 * p][vl];
      float v1 = ts[cig * 16 + 2 * p + 1][vl];
      ushort h0 = bf16_bits(v0), h1 = bf16_bits(v1);
      float r0 = v0 - __bfloat162float(*reinterpret_cast<__hip_bfloat16*>(&h0));
      float r1 = v1 - __bfloat162float(*reinterpret_cast<__hip_bfloat16*>(&h1));
      h[p] = (uint)h0 | ((uint)h1 << 16);
      l[p] = (uint)bf16_bits(r0) | ((uint)bf16_bits(r1) << 16);
    }
    size_t base = (size_t)(vox0 + vl) * 64 + cig * 16;
    *reinterpret_cast<uint4*>(xh + base)     = make_uint4(h[0], h[1], h[2], h[3]);
    *reinterpret_cast<uint4*>(xh + base + 8) = make_uint4(h[4], h[5], h[6], h[7]);
    *reinterpret_cast<uint4*>(xl + base)     = make_uint4(l[0], l[1], l[2], l[3]);
    *reinterpret_cast<uint4*>(xl + base + 8) = make_uint4(l[4], l[5], l[6], l[7]);
    return;
  }
  const int bid = blockIdx.x - 512;
  if (bid < 128) {
    int tid = bid * 256 + t;
    int oc = tid & 511, g = (tid >> 9) & 3, khalf = (tid >> 11) & 1, tap = tid >> 12;
    uint h[4], l[4];
#pragma unroll
    for (int p = 0; p < 4; ++p) {
      int ci0 = khalf * 32 + g * 8 + 2 * p;
      float v0 = vw[oc * 512 + ci0 * 8 + tap];
      float v1 = vw[oc * 512 + (ci0 + 1) * 8 + tap];
      ushort h0 = bf16_bits(v0), h1 = bf16_bits(v1);
      float r0 = v0 - __bfloat162float(*reinterpret_cast<__hip_bfloat16*>(&h0));
      float r1 = v1 - __bfloat162float(*reinterpret_cast<__hip_bfloat16*>(&h1));
      h[p] = (uint)h0 | ((uint)h1 << 16);
      l[p] = (uint)bf16_bits(r0) | ((uint)bf16_bits(r1) << 16);
    }
    size_t base = (size_t)tid * 8;
    *reinterpret_cast<uint4*>(wfh + base) = make_uint4(h[0], h[1], h[2], h[3]);
    *reinterpret_cast<uint4*>(wfl + base) = make_uint4(l[0], l[1], l[2], l[3]);
  } else if (bid < 136) {
    int tid = (bid - 128) * 256 + t;
    if (tid < 32) bqk[tid] = tid < 16 ? q1b[tid] : k1b[tid - 16];
    int oc = tid & 31, g = (tid >> 5) & 3, khalf = (tid >> 7) & 1, tap = tid >> 8;
    const float* src = oc < 16 ? q1w + oc * 512 : k1w + (oc - 16) * 512;
    uint h[4], l[4];
#pragma unroll
    for (int p = 0; p < 4; ++p) {
      int ci0 = khalf * 32 + g * 8 + 2 * p;
      float v0 = src[ci0 * 8 + tap];
      float v1 = src[(ci0 + 1) * 8 + tap];
      ushort h0 = bf16_bits(v0), h1 = bf16_bits(v1);
      float r0 = v0 - __bfloat162float(*reinterpret_cast<__hip_bfloat16*>(&h0));
      float r1 = v1 - __bfloat162float(*reinterpret_cast<__hip_bfloat16*>(&h1));
      h[p] = (uint)h0 | ((uint)h1 << 16);
      l[p] = (uint)bf16_bits(r0) | ((uint)bf16_bits(r1) << 16);
    }
    size_t base = (size_t)tid * 8;
    *reinterpret_cast<uint4*>(wqh + base) = make_uint4(h[0], h[1], h[2], h[3]);
    *reinterpret_cast<uint4*>(wql + base) = make_uint4(l[0], l[1], l[2], l[3]);
  } else {
    int tid = (bid - 136) * 256 + t;
    if (tid < 96) b96[tid] = tid < 64 ? q2b[tid] : (tid < 72 ? k2b[tid - 64] : 0.f);
    int oc = tid % 96, g = (tid / 96) & 3, kslot = tid / 384;
    int khalf = kslot & 1, tap = kslot >> 1;
    uint h[4], l[4];
#pragma unroll
    for (int p = 0; p < 4; ++p) {
      float v[2];
#pragma unroll
      for (int q = 0; q < 2; ++q) {
        int ci = khalf * 32 + g * 8 + 2 * p + q;
        float w = 0.f;
        if (ci < 16) { if (oc < 64) w = q2w[(oc * 16 + ci) * 8 + tap]; }
        else if (ci < 32) {
          if (oc >= 64 && oc < 72) w = k2w[((oc - 64) * 16 + (ci - 16)) * 8 + tap];
        }
        v[q] = w;
      }
      ushort h0 = bf16_bits(v[0]), h1 = bf16_bits(v[1]);
      float r0 = v[0] - __bfloat162float(*reinterpret_cast<__hip_bfloat16*>(&h0));
      float r1 = v[1] - __bfloat162float(*reinterpret_cast<__hip_bfloat16*>(&h1));
      h[p] = (uint)h0 | ((uint)h1 << 16);
      l[p] = (uint)bf16_bits(r0) | ((uint)bf16_bits(r1) << 16);
    }
    size_t base = (size_t)tid * 8;
    *reinterpret_cast<uint4*>(w2h + base) = make_uint4(h[0], h[1], h[2], h[3]);
    *reinterpret_cast<uint4*>(w2l + base) = make_uint4(l[0], l[1], l[2], l[3]);
  }
}

// ---------------------------------------------------------------------------
// Normalize q1/k1 -> [vox][64] bf16 hi/lo, ci 32..63 zeroed (unchanged).
// ---------------------------------------------------------------------------
__global__ __launch_bounds__(256) void xprep2_kernel(
    const float* __restrict__ qk1, const float* __restrict__ np,
    ushort* __restrict__ xh, ushort* __restrict__ xl)
{
  __shared__ float ts[32][65];
  const int t = threadIdx.x;
  const int vox0 = blockIdx.x * 64;
#pragma unroll
  for (int i = 0; i < 8; ++i) {
    int e = i * 256 + t;
    int ci = e >> 6, vl = e & 63;
    float m = np[2 * ci], rs = np[2 * ci + 1];
    float v = qk1[(size_t)ci * VOX + vox0 + vl];
    ts[ci][vl] = fmaxf((v - m) * rs, 0.f);
  }
  __syncthreads();
  const int vl = t >> 2, cig = t & 3;
  uint h[8], l[8];
#pragma unroll
  for (int p = 0; p < 8; ++p) {
    if (cig < 2) {
      float v0 = ts[cig * 16 + 2 * p][vl];
      float v1 = ts[cig * 16 + 2 * p + 1][vl];
      ushort h0 = bf16_bits(v0), h1 = bf16_bits(v1);
      float r0 = v0 - __bfloat162float(*reinterpret_cast<__hip_bfloat16*>(&h0));
      float r1 = v1 - __bfloat162float(*reinterpret_cast<__hip_bfloat16*>(&h1));
      h[p] = (uint)h0 | ((uint)h1 << 16);
      l[p] = (uint)bf16_bits(r0) | ((uint)bf16_bits(r1) << 16);
    } else { h[p] = 0u; l[p] = 0u; }
  }
  size_t base = (size_t)(vox0 + vl) * 64 + cig * 16;
  *reinterpret_cast<uint4*>(xh + base)     = make_uint4(h[0], h[1], h[2], h[3]);
  *reinterpret_cast<uint4*>(xh + base + 8) = make_uint4(h[4], h[5], h[6], h[7]);
  *reinterpret_cast<uint4*>(xl + base)     = make_uint4(l[0], l[1], l[2], l[3]);
  *reinterpret_cast<uint4*>(xl + base + 8) = make_uint4(l[4], l[5], l[6], l[7]);
}

// ---------------------------------------------------------------------------
// MFMA conv body (LDS-staged, proven).
// ---------------------------------------------------------------------------
template <int NMF, int OCS>
__device__ __forceinline__ void conv_mfma_body(
    ushort* Bs,
    const ushort* __restrict__ xh, const ushort* __restrict__ xl,
    const ushort* __restrict__ wh, const ushort* __restrict__ wl,
    const float* __restrict__ bias, float* __restrict__ y,
    float* __restrict__ part, int bx, int nt, int t)
{
  const int wave = t >> 6, lane = t & 63;
  const int wm = wave >> 1, wn = wave & 1;
  const int g = lane >> 4, ww = lane & 15;
  const int m0 = bx * (NMF * 32);
  const int td = nt >> 4, th = (nt >> 1) & 7, tw = nt & 1;
  const int d0 = td * 2, h0 = th * 4, w0 = tw * 16;

  for (int i = 0; i < 16; ++i) {
    int c = i * 256 + t;
    if (c < 4080) {
      int split = (c >= 2040) ? 1 : 0;
      int c2 = c - split * 2040;
      int pos = c2 >> 3, cig = c2 & 7;
      int dz = pos / 85, rem = pos - dz * 85;
      int hz = rem / 17, wz = rem - hz * 17;
      int d = d0 + dz, h = h0 + hz, w = w0 + wz;
      uint4 val = make_uint4(0, 0, 0, 0);
      if (d < 32 && h < 32 && w < 32) {
        const ushort* src = split ? xl : xh;
        val = *reinterpret_cast<const uint4*>(
            src + (size_t)(d * 1024 + h * 32 + w) * 64 + cig * 8);
      }
      int addr = (pos << 7) + cig * 16;
      addr ^= (pos & 7) << 4;
      *reinterpret_cast<uint4*>(
          reinterpret_cast<char*>(Bs) + split * 32640 + addr) = val;
    }
  }
  __syncthreads();

  const int ocl = m0 + wm * (NMF * 16) + ww;
  f32x4 acc[NMF][4];
#pragma unroll
  for (int mf = 0; mf < NMF; ++mf)
#pragma unroll
    for (int hh = 0; hh < 4; ++hh) acc[mf][hh] = (f32x4){0.f, 0.f, 0.f, 0.f};

  for (int tap = 0; tap < 8; ++tap) {
    const int kd = tap >> 2, kh = (tap >> 1) & 1, kw = tap & 1;
#pragma unroll
    for (int khalf = 0; khalf < 2; ++khalf) {
      const size_t abase = ((size_t)((tap * 2 + khalf) * 4 + g) * OCS + ocl) * 8;
      s16x8 Ah[NMF], Al[NMF];
#pragma unroll
      for (int mf = 0; mf < NMF; ++mf) {
        Ah[mf] = *reinterpret_cast<const s16x8*>(wh + abase + mf * 16 * 8);
        Al[mf] = *reinterpret_cast<const s16x8*>(wl + abase + mf * 16 * 8);
      }
      const int srow = ((wn + kd) * 5 + kh) * 17 + kw;
#pragma unroll
      for (int hh = 0; hh < 4; ++hh) {
        int pos = srow + hh * 17 + ww;
        int baddr = (pos << 7) + khalf * 64 + g * 16;
        baddr ^= (pos & 7) << 4;
        const char* bp = reinterpret_cast<const char*>(Bs) + baddr;
        s16x8 Bh = *reinterpret_cast<const s16x8*>(bp);
        s16x8 Bl = *reinterpret_cast<const s16x8*>(bp + 32640);
#pragma unroll
        for (int mf = 0; mf < NMF; ++mf) {
          acc[mf][hh] = __builtin_amdgcn_mfma_f32_16x16x32_bf16(
              Ah[mf], Bh, acc[mf][hh], 0, 0, 0);
          acc[mf][hh] = __builtin_amdgcn_mfma_f32_16x16x32_bf16(
              Al[mf], Bh, acc[mf][hh], 0, 0, 0);
          acc[mf][hh] = __builtin_amdgcn_mfma_f32_16x16x32_bf16(
              Ah[mf], Bl, acc[mf][hh], 0, 0, 0);
        }
      }
    }
  }

  float bs[NMF][4];
#pragma unroll
  for (int mf = 0; mf < NMF; ++mf)
#pragma unroll
    for (int reg = 0; reg < 4; ++reg)
      bs[mf][reg] = bias[m0 + wm * (NMF * 16) + mf * 16 + g * 4 + reg];

  float ssum[NMF][4], ssq[NMF][4];
#pragma unroll
  for (int mf = 0; mf < NMF; ++mf)
#pragma unroll
    for (int reg = 0; reg < 4; ++reg) { ssum[mf][reg] = 0.f; ssq[mf][reg] = 0.f; }

#pragma unroll
  for (int mf = 0; mf < NMF; ++mf) {
#pragma unroll
    for (int hh = 0; hh < 4; ++hh) {
      int vox = (d0 + wn) * 1024 + (h0 + hh) * 32 + w0 + ww;
#pragma unroll
      for (int reg = 0; reg < 4; ++reg) {
        float v = acc[mf][hh][reg] + bs[mf][reg];
        int oc = m0 + wm * (NMF * 16) + mf * 16 + g * 4 + reg;
        y[(size_t)oc * VOX + vox] = v;
        ssum[mf][reg] += v;
        ssq[mf][reg] += v * v;
      }
    }
  }
#pragma unroll
  for (int mf = 0; mf < NMF; ++mf)
#pragma unroll
    for (int reg = 0; reg < 4; ++reg)
#pragma unroll
      for (int off = 1; off < 16; off <<= 1) {
        ssum[mf][reg] += __shfl_xor(ssum[mf][reg], off);
        ssq[mf][reg]  += __shfl_xor(ssq[mf][reg], off);
      }
  if ((lane & 15) == 0) {
    float* pp = part + (size_t)(nt * 2 + wn) * (OCS * 2);
#pragma unroll
    for (int mf = 0; mf < NMF; ++mf)
#pragma unroll
      for (int reg = 0; reg < 4; ++reg) {
        int oc = m0 + wm * (NMF * 16) + mf * 16 + g * 4 + reg;
        pp[oc * 2]     = ssum[mf][reg];
        pp[oc * 2 + 1] = ssq[mf][reg];
      }
  }
}

__global__ __launch_bounds__(256) void conv_fused_kernel(
    const ushort* __restrict__ xh, const ushort* __restrict__ xl,
    const ushort* __restrict__ wfh, const ushort* __restrict__ wfl,
    const float* __restrict__ vb, float* __restrict__ vraw,
    float* __restrict__ part_v,
    const ushort* __restrict__ wqh, const ushort* __restrict__ wql,
    const float* __restrict__ bqk, float* __restrict__ qk1,
    float* __restrict__ part_qk)
{
  __shared__ ushort Bs[2 * 255 * 64];
  const int bx = blockIdx.x, nt = blockIdx.y, t = threadIdx.x;
  if (bx < 2)
    conv_mfma_body<8, 512>(Bs, xh, xl, wfh, wfl, vb, vraw, part_v, bx, nt, t);
  else
    conv_mfma_body<1, 32>(Bs, xh, xl, wqh, wql, bqk, qk1, part_qk, 0, nt, t);
}

template <int NMF, int OCS>
__global__ __launch_bounds__(256) void conv_v_mfma(
    const ushort* __restrict__ xh, const ushort* __restrict__ xl,
    const ushort* __restrict__ wh, const ushort* __restrict__ wl,
    const float* __restrict__ bias, float* __restrict__ y,
    float* __restrict__ part)
{
  __shared__ ushort Bs[2 * 255 * 64];
  conv_mfma_body<NMF, OCS>(Bs, xh, xl, wh, wl, bias, y, part,
                           blockIdx.x, blockIdx.y, threadIdx.x);
}

// ---------------------------------------------------------------------------
// finalize3 v3: 16 channels/block x 16 workers/channel, shfl reduce.
// ---------------------------------------------------------------------------
__global__ __launch_bounds__(256) void finalize3_kernel(
    const float* __restrict__ p1, int C1, int NT1, float* __restrict__ n1,
    const float* __restrict__ p2, int C2, int NT2, float* __restrict__ n2,
    const float* __restrict__ p3, int C3, int NT3, float* __restrict__ n3)
{
  const int t = threadIdx.x;
  const int chl = t >> 4, w = t & 15;
  const int g = blockIdx.x * 16 + chl;

  const float* part = nullptr; float* np = nullptr; int C = 0, NT = 0, c = 0;
  if (g < C1)                { part = p1; np = n1; C = C1; NT = NT1; c = g; }
  else if (g < C1 + C2)      { part = p2; np = n2; C = C2; NT = NT2; c = g - C1; }
  else if (g < C1 + C2 + C3) { part = p3; np = n3; C = C3; NT = NT3; c = g - C1 - C2; }

  float s = 0.f, ss = 0.f;
  if (part)
    for (int tile = w; tile < NT; tile += 16) {
      float2 v = *reinterpret_cast<const float2*>(&part[((size_t)tile * C + c) * 2]);
      s += v.x; ss += v.y;
    }
#pragma unroll
  for (int off = 1; off < 16; off <<= 1) {
    s  += __shfl_xor(s, off);
    ss += __shfl_xor(ss, off);
  }
  if (w == 0 && part) {
    float m = s * INV_VOX;
    float var = ss * INV_VOX - m * m;
    np[2 * c]     = m;
    np[2 * c + 1] = rsqrtf(var + EPSF);
  }
}

// ---------------------------------------------------------------------------
// qk_box v2 (unchanged).
// ---------------------------------------------------------------------------
__global__ __launch_bounds__(256) void qk_box_kernel(
    const float* __restrict__ qraw, const float* __restrict__ npq,
    const float* __restrict__ kraw, const float* __restrict__ npk,
    float* __restrict__ qkout)
{
  __shared__ float s[1000];
  __shared__ float ws2[800];
  const int j = blockIdx.y;
  const int tile = blockIdx.x;
  const int W0 = (tile & 7) * 8, H0 = ((tile >> 3) & 7) * 8, D0 = (tile >> 6) * 8;
  const int t = threadIdx.x;
  const int cbD = (D0 >> 1) - 1, cbH = (H0 >> 1) - 1, cbW = (W0 >> 1) - 1;
  const float2* npq2 = reinterpret_cast<const float2*>(npq);
  const float2* npk2 = reinterpret_cast<const float2*>(npk);

#pragma unroll
  for (int kk = 0; kk < 7; ++kk) {
    int f = t + kk * 256;
    if (f < 1728) {
      int par = f / 216, idx = f - par * 216;
      int dz = idx / 36, r2 = idx - dz * 36, hz = r2 / 6, wz = r2 - hz * 6;
      int pd = (par >> 2) & 1, ph = (par >> 1) & 1, pw = par & 1;
      int dzf = 2 * dz + pd - 1, hzf = 2 * hz + ph - 1, wzf = 2 * wz + pw - 1;
      if ((unsigned)dzf < 10u && (unsigned)hzf < 10u && (unsigned)wzf < 10u) {
        int cD = cbD + dz, cH = cbH + hz, cW = cbW + wz;
        float prod = 0.f;
        if ((unsigned)cD < 32u && (unsigned)cH < 32u && (unsigned)cW < 32u) {
          int cidx = cD * 1024 + cH * 32 + cW;
          int qc = j * 8 + par;
          float2 nq = npq2[qc];
          float2 nk = npk2[par];
          float qv = fmaxf((qraw[(size_t)qc * VOX + cidx] - nq.x) * nq.y, 0.f);
          float kv = fmaxf((kraw[(size_t)par * VOX + cidx] - nk.x) * nk.y, 0.f);
          prod = qv * kv;
        }
        s[dzf * 100 + hzf * 10 + wzf] = prod;
      }
    }
  }
  __syncthreads();
#pragma unroll
  for (int i = 0; i < 4; ++i) {
    int e = t + i * 256;
    if (e < 800) {
      int dz = e / 80, r2 = e - dz * 80, hz = r2 >> 3, wz1 = r2 & 7;
      int base = dz * 100 + hz * 10 + wz1;
      ws2[e] = s[base] + s[base + 1] + s[base + 2];
    }
  }
  __syncthreads();
#pragma unroll
  for (int rep = 0; rep < 2; ++rep) {
    int o = t + rep * 256;
    int wz = o & 7, hz = (o >> 3) & 7, dz = o >> 6;
    int wb = dz * 80 + hz * 8 + wz;
    float sum = 0.f;
#pragma unroll
    for (int a = 0; a < 3; ++a)
      sum += ws2[wb + a * 80] + ws2[wb + a * 80 + 8] + ws2[wb + a * 80 + 16];
    qkout[(size_t)j * 262144 + (D0 + dz) * 4096 + (H0 + hz) * 64 + (W0 + wz)] =
        sum * (1.f / 27.f);
  }
}

// ---------------------------------------------------------------------------
// einsum_box v11: NO vs staging; v read directly from L2-resident vraw.
// grid (4 = cHalf*2+ciHalf, 512 tiles), 256 thr, 16 channels/block.
// LDS: qkvs[1000] + wsum[800] only. 3 barriers/iter.
// ---------------------------------------------------------------------------
__global__ __launch_bounds__(256) void einsum_box_kernel(
    const float* __restrict__ vraw, const float* __restrict__ npv,
    const float* __restrict__ qk, float* __restrict__ out)
{
  __shared__ float qkvs[1000];
  __shared__ float wsum[800];

  const int c0 = (blockIdx.x & 1) * 32;
  const int ciBase = ((blockIdx.x >> 1) & 1) * 16;
  const int tile = blockIdx.y;
  const int W0 = (tile & 7) * 8, H0 = ((tile >> 3) & 7) * 8, D0 = (tile >> 6) * 8;
  const int t = threadIdx.x;
  const float2* npv2 = reinterpret_cast<const float2*>(npv);

  // qkv-slot precompute: qk -> registers, coarse global offset per slot
  uint voff[4]; float qr[4][8];
#pragma unroll
  for (int i = 0; i < 4; ++i) {
    int pos = t + i * 256;
    voff[i] = 0u;
#pragma unroll
    for (int j = 0; j < 8; ++j) qr[i][j] = 0.f;
    if (pos < 1000) {
      int dz = pos / 100, rem = pos - dz * 100, hz = rem / 10, wz = rem - hz * 10;
      int D = D0 - 1 + dz, H = H0 - 1 + hz, W = W0 - 1 + wz;
      if ((unsigned)D < 64u && (unsigned)H < 64u && (unsigned)W < 64u) {
        int fidx = D * 4096 + H * 64 + W;
#pragma unroll
        for (int j = 0; j < 8; ++j)
          qr[i][j] = qk[(size_t)j * 262144 + fidx];
        voff[i] = (uint)((D >> 1) * 1024 + (H >> 1) * 32 + (W >> 1));
      }
    }
  }

  int wb[4];
#pragma unroll
  for (int i = 0; i < 4; ++i) {
    int e = t + i * 256;
    int dz = e / 80, r2 = e - dz * 80, hz = r2 >> 3, wz1 = r2 & 7;
    wb[i] = dz * 100 + hz * 10 + wz1;
  }
  int wb2[2]; float* op[2];
#pragma unroll
  for (int rep = 0; rep < 2; ++rep) {
    int o = t + rep * 256;
    int wz = o & 7, hz = (o >> 3) & 7, dz = o >> 6;
    wb2[rep] = dz * 80 + hz * 8 + wz;
    op[rep] = out + (size_t)c0 * 262144 +
              (D0 + dz) * 4096 + (H0 + hz) * 64 + (W0 + wz);
  }

  for (int li = 0; li < 16; ++li) {
    const int ci = ciBase + li;
    const size_t cbase = (size_t)(c0 + ci) * 8 * VOX;
    float mj[8], rj[8];
#pragma unroll
    for (int j = 0; j < 8; ++j) {
      float2 nv = npv2[(c0 + ci) * 8 + j];   // wave-uniform -> s_loads
      mj[j] = nv.x; rj[j] = nv.y;
    }
    // phase B: qkv from direct global v loads (L2-resident tile)
#pragma unroll
    for (int i = 0; i < 4; ++i) {
      int pos = t + i * 256;
      if (pos < 1000) {
        const float* vp = vraw + cbase + voff[i];
        float val = 0.f;
#pragma unroll
        for (int j = 0; j < 8; ++j) {
          float raw = vp[(size_t)j * VOX];
          float vn = fmaxf((raw - mj[j]) * rj[j], 0.f);
          val = fmaf(qr[i][j], vn, val);
        }
        qkvs[pos] = val;
      }
    }
    __syncthreads();   // barrier 1: qkvs ready
    // W-pass
#pragma unroll
    for (int i = 0; i < 4; ++i) {
      if (i < 3 || t < 32) {
        int b = wb[i];
        wsum[t + i * 256] = qkvs[b] + qkvs[b + 1] + qkvs[b + 2];
      }
    }
    __syncthreads();   // barrier 2: wsum ready
    // H+D gather + store
#pragma unroll
    for (int rep = 0; rep < 2; ++rep) {
      float sum = 0.f;
#pragma unroll
      for (int a = 0; a < 3; ++a)
        sum += wsum[wb2[rep] + a * 80] + wsum[wb2[rep] + a * 80 + 8] +
               wsum[wb2[rep] + a * 80 + 16];
      op[rep][(size_t)ci << 18] = sum * (1.f / 27.f);
    }
    __syncthreads();   // barrier 3: box reads done before qkvs overwrite
  }
}

// ---------------------------------------------------------------------------
extern "C" void kernel_launch(void* const* d_in, const int* in_sizes, int n_in,
                              void* d_out, int out_size, void* d_ws, size_t ws_size,
                              hipStream_t stream)
{
  (void)in_sizes; (void)n_in; (void)out_size; (void)ws_size;
  const float* x   = (const float*)d_in[0];
  const float* q1w = (const float*)d_in[1];
  const float* q1b = (const float*)d_in[2];
  const float* q2w = (const float*)d_in[3];
  const float* q2b = (const float*)d_in[4];
  const float* k1w = (const float*)d_in[5];
  const float* k1b = (const float*)d_in[6];
  const float* k2w = (const float*)d_in[7];
  const float* k2b = (const float*)d_in[8];
  const float* vw  = (const float*)d_in[9];
  const float* vb  = (const float*)d_in[10];
  float* out = (float*)d_out;

  float* p = (float*)d_ws;
  float* vraw    = p; p += (size_t)512 * VOX;      // 64 MiB
  float* regionR = p; p += (size_t)96 * VOX;       // 12 MiB: qk1raw then y96
  float* qkbuf   = p; p += (size_t)8 * 262144;     // 8 MiB: xT / xT2 / qk
  float* part_v  = p; p += (size_t)512 * 512 * 2;
  float* part_qk = p; p += (size_t)512 * 32 * 2;
  float* part96  = p; p += (size_t)512 * 96 * 2;
  float* WfF     = p; p += (size_t)262144;
  float* WqF     = p; p += (size_t)16384;
  float* W2F     = p; p += (size_t)49152;
  float* np_qk1  = p; p += 64;
  float* np96    = p; p += 192;
  float* np_v    = p; p += 1024;
  float* bqk     = p; p += 32;
  float* b96     = p; p += 96;

  float* qk1raw = regionR;
  float* y96    = regionR;

  ushort* xT_hi = (ushort*)qkbuf;
  ushort* xT_lo = (ushort*)qkbuf + (size_t)32768 * 64;
  ushort* Wf_hi = (ushort*)WfF;
  ushort* Wf_lo = (ushort*)WfF + 262144;
  ushort* Wq_hi = (ushort*)WqF;
  ushort* Wq_lo = (ushort*)WqF + 16384;
  ushort* W2_hi = (ushort*)W2F;
  ushort* W2_lo = (ushort*)W2F + 49152;

  dim3 blk(256);
  prep_all_kernel<<<672, blk, 0, stream>>>(
      x, vw, q1w, q1b, k1w, k1b, q2w, q2b, k2w, k2b,
      xT_hi, xT_lo, Wf_hi, Wf_lo, Wq_hi, Wq_lo, bqk, W2_hi, W2_lo, b96);
  conv_fused_kernel<<<dim3(3, 256), blk, 0, stream>>>(
      xT_hi, xT_lo, Wf_hi, Wf_lo, vb, vraw, part_v,
      Wq_hi, Wq_lo, bqk, qk1raw, part_qk);
  finalize3_kernel<<<34, blk, 0, stream>>>(
      part_v, 512, 512, np_v,
      part_qk, 32, 512, np_qk1,
      nullptr, 0, 0, nullptr);
  xprep2_kernel<<<512, blk, 0, stream>>>(qk1raw, np_qk1, xT_hi, xT_lo);
  conv_v_mfma<3, 96><<<dim3(1, 256), blk, 0, stream>>>(
      xT_hi, xT_lo, W2_hi, W2_lo, b96, y96, part96);
  finalize3_kernel<<<6, blk, 0, stream>>>(
      part96, 96, 512, np96,
      nullptr, 0, 0, nullptr,
      nullptr, 0, 0, nullptr);
  qk_box_kernel<<<dim3(512, 8), blk, 0, stream>>>(
      y96, np96, y96 + (size_t)64 * VOX, np96 + 128, qkbuf);
  einsum_box_kernel<<<dim3(4, 512), blk, 0, stream>>>(
      vraw, np_v, qkbuf, out);
}

// Round 19
// 284.494 us; speedup vs baseline: 1.3200x; 1.3200x over previous
//
#include <hip/hip_runtime.h>
#include <hip/hip_bf16.h>

// QKV upsampling pipeline.
// R19: einsum v12 -- coarse-voxel-per-thread. Each thread owns one of 216
// coarse voxels: loads its 8 j-values from global ONCE per channel (1728
// loads/iter = v7's staging count) and computes its <=8 fine qkv outputs
// from register-held qk weights. No vs array (v11's LDS win) without v11's
// 4.6x VMEM amplification. wsum/box phases = proven v10. Rest = R16 (278us).

constexpr int VOX = 32 * 32 * 32;
constexpr float INV_VOX = 1.0f / 32768.0f;
constexpr float EPSF = 1e-5f;

typedef __attribute__((ext_vector_type(8))) short s16x8;
typedef __attribute__((ext_vector_type(4))) float f32x4;

static __device__ __forceinline__ ushort bf16_bits(float v) {
  __hip_bfloat16 h = __float2bfloat16(v);
  return *reinterpret_cast<ushort*>(&h);
}

// ---------------------------------------------------------------------------
// Merged x-transpose (blocks 0-511) + weight prepack (blocks 512-671).
// ---------------------------------------------------------------------------
__global__ __launch_bounds__(256) void prep_all_kernel(
    const float* __restrict__ x,
    const float* __restrict__ vw,
    const float* __restrict__ q1w, const float* __restrict__ q1b,
    const float* __restrict__ k1w, const float* __restrict__ k1b,
    const float* __restrict__ q2w, const float* __restrict__ q2b,
    const float* __restrict__ k2w, const float* __restrict__ k2b,
    ushort* __restrict__ xh, ushort* __restrict__ xl,
    ushort* __restrict__ wfh, ushort* __restrict__ wfl,
    ushort* __restrict__ wqh, ushort* __restrict__ wql, float* __restrict__ bqk,
    ushort* __restrict__ w2h, ushort* __restrict__ w2l, float* __restrict__ b96)
{
  __shared__ float ts[64][65];
  const int t = threadIdx.x;
  if ((int)blockIdx.x < 512) {
    const int vox0 = blockIdx.x * 64;
#pragma unroll
    for (int i = 0; i < 16; ++i) {
      int e = i * 256 + t;
      int ci = e >> 6, vl = e & 63;
      ts[ci][vl] = x[(size_t)ci * VOX + vox0 + vl];
    }
    __syncthreads();
    const int vl = t >> 2, cig = t & 3;
    uint h[8], l[8];
#pragma unroll
    for (int p = 0; p < 8; ++p) {
      float v0 = ts[cig * 16 + 2 * p][vl];
      float v1 = ts[cig * 16 + 2 * p + 1][vl];
      ushort h0 = bf16_bits(v0), h1 = bf16_bits(v1);
      float r0 = v0 - __bfloat162float(*reinterpret_cast<__hip_bfloat16*>(&h0));
      float r1 = v1 - __bfloat162float(*reinterpret_cast<__hip_bfloat16*>(&h1));
      h[p] = (uint)h0 | ((uint)h1 << 16);
      l[p] = (uint)bf16_bits(r0) | ((uint)bf16_bits(r1) << 16);
    }
    size_t base = (size_t)(vox0 + vl) * 64 + cig * 16;
    *reinterpret_cast<uint4*>(xh + base)     = make_uint4(h[0], h[1], h[2], h[3]);
    *reinterpret_cast<uint4*>(xh + base + 8) = make_uint4(h[4], h[5], h[6], h[7]);
    *reinterpret_cast<uint4*>(xl + base)     = make_uint4(l[0], l[1], l[2], l[3]);
    *reinterpret_cast<uint4*>(xl + base + 8) = make_uint4(l[4], l[5], l[6], l[7]);
    return;
  }
  const int bid = blockIdx.x - 512;
  if (bid < 128) {
    int tid = bid * 256 + t;
    int oc = tid & 511, g = (tid >> 9) & 3, khalf = (tid >> 11) & 1, tap = tid >> 12;
    uint h[4], l[4];
#pragma unroll
    for (int p = 0; p < 4; ++p) {
      int ci0 = khalf * 32 + g * 8 + 2 * p;
      float v0 = vw[oc * 512 + ci0 * 8 + tap];
      float v1 = vw[oc * 512 + (ci0 + 1) * 8 + tap];
      ushort h0 = bf16_bits(v0), h1 = bf16_bits(v1);
      float r0 = v0 - __bfloat162float(*reinterpret_cast<__hip_bfloat16*>(&h0));
      float r1 = v1 - __bfloat162float(*reinterpret_cast<__hip_bfloat16*>(&h1));
      h[p] = (uint)h0 | ((uint)h1 << 16);
      l[p] = (uint)bf16_bits(r0) | ((uint)bf16_bits(r1) << 16);
    }
    size_t base = (size_t)tid * 8;
    *reinterpret_cast<uint4*>(wfh + base) = make_uint4(h[0], h[1], h[2], h[3]);
    *reinterpret_cast<uint4*>(wfl + base) = make_uint4(l[0], l[1], l[2], l[3]);
  } else if (bid < 136) {
    int tid = (bid - 128) * 256 + t;
    if (tid < 32) bqk[tid] = tid < 16 ? q1b[tid] : k1b[tid - 16];
    int oc = tid & 31, g = (tid >> 5) & 3, khalf = (tid >> 7) & 1, tap = tid >> 8;
    const float* src = oc < 16 ? q1w + oc * 512 : k1w + (oc - 16) * 512;
    uint h[4], l[4];
#pragma unroll
    for (int p = 0; p < 4; ++p) {
      int ci0 = khalf * 32 + g * 8 + 2 * p;
      float v0 = src[ci0 * 8 + tap];
      float v1 = src[(ci0 + 1) * 8 + tap];
      ushort h0 = bf16_bits(v0), h1 = bf16_bits(v1);
      float r0 = v0 - __bfloat162float(*reinterpret_cast<__hip_bfloat16*>(&h0));
      float r1 = v1 - __bfloat162float(*reinterpret_cast<__hip_bfloat16*>(&h1));
      h[p] = (uint)h0 | ((uint)h1 << 16);
      l[p] = (uint)bf16_bits(r0) | ((uint)bf16_bits(r1) << 16);
    }
    size_t base = (size_t)tid * 8;
    *reinterpret_cast<uint4*>(wqh + base) = make_uint4(h[0], h[1], h[2], h[3]);
    *reinterpret_cast<uint4*>(wql + base) = make_uint4(l[0], l[1], l[2], l[3]);
  } else {
    int tid = (bid - 136) * 256 + t;
    if (tid < 96) b96[tid] = tid < 64 ? q2b[tid] : (tid < 72 ? k2b[tid - 64] : 0.f);
    int oc = tid % 96, g = (tid / 96) & 3, kslot = tid / 384;
    int khalf = kslot & 1, tap = kslot >> 1;
    uint h[4], l[4];
#pragma unroll
    for (int p = 0; p < 4; ++p) {
      float v[2];
#pragma unroll
      for (int q = 0; q < 2; ++q) {
        int ci = khalf * 32 + g * 8 + 2 * p + q;
        float w = 0.f;
        if (ci < 16) { if (oc < 64) w = q2w[(oc * 16 + ci) * 8 + tap]; }
        else if (ci < 32) {
          if (oc >= 64 && oc < 72) w = k2w[((oc - 64) * 16 + (ci - 16)) * 8 + tap];
        }
        v[q] = w;
      }
      ushort h0 = bf16_bits(v[0]), h1 = bf16_bits(v[1]);
      float r0 = v[0] - __bfloat162float(*reinterpret_cast<__hip_bfloat16*>(&h0));
      float r1 = v[1] - __bfloat162float(*reinterpret_cast<__hip_bfloat16*>(&h1));
      h[p] = (uint)h0 | ((uint)h1 << 16);
      l[p] = (uint)bf16_bits(r0) | ((uint)bf16_bits(r1) << 16);
    }
    size_t base = (size_t)tid * 8;
    *reinterpret_cast<uint4*>(w2h + base) = make_uint4(h[0], h[1], h[2], h[3]);
    *reinterpret_cast<uint4*>(w2l + base) = make_uint4(l[0], l[1], l[2], l[3]);
  }
}

// ---------------------------------------------------------------------------
// Normalize q1/k1 -> [vox][64] bf16 hi/lo, ci 32..63 zeroed (unchanged).
// ---------------------------------------------------------------------------
__global__ __launch_bounds__(256) void xprep2_kernel(
    const float* __restrict__ qk1, const float* __restrict__ np,
    ushort* __restrict__ xh, ushort* __restrict__ xl)
{
  __shared__ float ts[32][65];
  const int t = threadIdx.x;
  const int vox0 = blockIdx.x * 64;
#pragma unroll
  for (int i = 0; i < 8; ++i) {
    int e = i * 256 + t;
    int ci = e >> 6, vl = e & 63;
    float m = np[2 * ci], rs = np[2 * ci + 1];
    float v = qk1[(size_t)ci * VOX + vox0 + vl];
    ts[ci][vl] = fmaxf((v - m) * rs, 0.f);
  }
  __syncthreads();
  const int vl = t >> 2, cig = t & 3;
  uint h[8], l[8];
#pragma unroll
  for (int p = 0; p < 8; ++p) {
    if (cig < 2) {
      float v0 = ts[cig * 16 + 2 * p][vl];
      float v1 = ts[cig * 16 + 2 * p + 1][vl];
      ushort h0 = bf16_bits(v0), h1 = bf16_bits(v1);
      float r0 = v0 - __bfloat162float(*reinterpret_cast<__hip_bfloat16*>(&h0));
      float r1 = v1 - __bfloat162float(*reinterpret_cast<__hip_bfloat16*>(&h1));
      h[p] = (uint)h0 | ((uint)h1 << 16);
      l[p] = (uint)bf16_bits(r0) | ((uint)bf16_bits(r1) << 16);
    } else { h[p] = 0u; l[p] = 0u; }
  }
  size_t base = (size_t)(vox0 + vl) * 64 + cig * 16;
  *reinterpret_cast<uint4*>(xh + base)     = make_uint4(h[0], h[1], h[2], h[3]);
  *reinterpret_cast<uint4*>(xh + base + 8) = make_uint4(h[4], h[5], h[6], h[7]);
  *reinterpret_cast<uint4*>(xl + base)     = make_uint4(l[0], l[1], l[2], l[3]);
  *reinterpret_cast<uint4*>(xl + base + 8) = make_uint4(l[4], l[5], l[6], l[7]);
}

// ---------------------------------------------------------------------------
// MFMA conv body (LDS-staged, proven).
// ---------------------------------------------------------------------------
template <int NMF, int OCS>
__device__ __forceinline__ void conv_mfma_body(
    ushort* Bs,
    const ushort* __restrict__ xh, const ushort* __restrict__ xl,
    const ushort* __restrict__ wh, const ushort* __restrict__ wl,
    const float* __restrict__ bias, float* __restrict__ y,
    float* __restrict__ part, int bx, int nt, int t)
{
  const int wave = t >> 6, lane = t & 63;
  const int wm = wave >> 1, wn = wave & 1;
  const int g = lane >> 4, ww = lane & 15;
  const int m0 = bx * (NMF * 32);
  const int td = nt >> 4, th = (nt >> 1) & 7, tw = nt & 1;
  const int d0 = td * 2, h0 = th * 4, w0 = tw * 16;

  for (int i = 0; i < 16; ++i) {
    int c = i * 256 + t;
    if (c < 4080) {
      int split = (c >= 2040) ? 1 : 0;
      int c2 = c - split * 2040;
      int pos = c2 >> 3, cig = c2 & 7;
      int dz = pos / 85, rem = pos - dz * 85;
      int hz = rem / 17, wz = rem - hz * 17;
      int d = d0 + dz, h = h0 + hz, w = w0 + wz;
      uint4 val = make_uint4(0, 0, 0, 0);
      if (d < 32 && h < 32 && w < 32) {
        const ushort* src = split ? xl : xh;
        val = *reinterpret_cast<const uint4*>(
            src + (size_t)(d * 1024 + h * 32 + w) * 64 + cig * 8);
      }
      int addr = (pos << 7) + cig * 16;
      addr ^= (pos & 7) << 4;
      *reinterpret_cast<uint4*>(
          reinterpret_cast<char*>(Bs) + split * 32640 + addr) = val;
    }
  }
  __syncthreads();

  const int ocl = m0 + wm * (NMF * 16) + ww;
  f32x4 acc[NMF][4];
#pragma unroll
  for (int mf = 0; mf < NMF; ++mf)
#pragma unroll
    for (int hh = 0; hh < 4; ++hh) acc[mf][hh] = (f32x4){0.f, 0.f, 0.f, 0.f};

  for (int tap = 0; tap < 8; ++tap) {
    const int kd = tap >> 2, kh = (tap >> 1) & 1, kw = tap & 1;
#pragma unroll
    for (int khalf = 0; khalf < 2; ++khalf) {
      const size_t abase = ((size_t)((tap * 2 + khalf) * 4 + g) * OCS + ocl) * 8;
      s16x8 Ah[NMF], Al[NMF];
#pragma unroll
      for (int mf = 0; mf < NMF; ++mf) {
        Ah[mf] = *reinterpret_cast<const s16x8*>(wh + abase + mf * 16 * 8);
        Al[mf] = *reinterpret_cast<const s16x8*>(wl + abase + mf * 16 * 8);
      }
      const int srow = ((wn + kd) * 5 + kh) * 17 + kw;
#pragma unroll
      for (int hh = 0; hh < 4; ++hh) {
        int pos = srow + hh * 17 + ww;
        int baddr = (pos << 7) + khalf * 64 + g * 16;
        baddr ^= (pos & 7) << 4;
        const char* bp = reinterpret_cast<const char*>(Bs) + baddr;
        s16x8 Bh = *reinterpret_cast<const s16x8*>(bp);
        s16x8 Bl = *reinterpret_cast<const s16x8*>(bp + 32640);
#pragma unroll
        for (int mf = 0; mf < NMF; ++mf) {
          acc[mf][hh] = __builtin_amdgcn_mfma_f32_16x16x32_bf16(
              Ah[mf], Bh, acc[mf][hh], 0, 0, 0);
          acc[mf][hh] = __builtin_amdgcn_mfma_f32_16x16x32_bf16(
              Al[mf], Bh, acc[mf][hh], 0, 0, 0);
          acc[mf][hh] = __builtin_amdgcn_mfma_f32_16x16x32_bf16(
              Ah[mf], Bl, acc[mf][hh], 0, 0, 0);
        }
      }
    }
  }

  float bs[NMF][4];
#pragma unroll
  for (int mf = 0; mf < NMF; ++mf)
#pragma unroll
    for (int reg = 0; reg < 4; ++reg)
      bs[mf][reg] = bias[m0 + wm * (NMF * 16) + mf * 16 + g * 4 + reg];

  float ssum[NMF][4], ssq[NMF][4];
#pragma unroll
  for (int mf = 0; mf < NMF; ++mf)
#pragma unroll
    for (int reg = 0; reg < 4; ++reg) { ssum[mf][reg] = 0.f; ssq[mf][reg] = 0.f; }

#pragma unroll
  for (int mf = 0; mf < NMF; ++mf) {
#pragma unroll
    for (int hh = 0; hh < 4; ++hh) {
      int vox = (d0 + wn) * 1024 + (h0 + hh) * 32 + w0 + ww;
#pragma unroll
      for (int reg = 0; reg < 4; ++reg) {
        float v = acc[mf][hh][reg] + bs[mf][reg];
        int oc = m0 + wm * (NMF * 16) + mf * 16 + g * 4 + reg;
        y[(size_t)oc * VOX + vox] = v;
        ssum[mf][reg] += v;
        ssq[mf][reg] += v * v;
      }
    }
  }
#pragma unroll
  for (int mf = 0; mf < NMF; ++mf)
#pragma unroll
    for (int reg = 0; reg < 4; ++reg)
#pragma unroll
      for (int off = 1; off < 16; off <<= 1) {
        ssum[mf][reg] += __shfl_xor(ssum[mf][reg], off);
        ssq[mf][reg]  += __shfl_xor(ssq[mf][reg], off);
      }
  if ((lane & 15) == 0) {
    float* pp = part + (size_t)(nt * 2 + wn) * (OCS * 2);
#pragma unroll
    for (int mf = 0; mf < NMF; ++mf)
#pragma unroll
      for (int reg = 0; reg < 4; ++reg) {
        int oc = m0 + wm * (NMF * 16) + mf * 16 + g * 4 + reg;
        pp[oc * 2]     = ssum[mf][reg];
        pp[oc * 2 + 1] = ssq[mf][reg];
      }
  }
}

__global__ __launch_bounds__(256) void conv_fused_kernel(
    const ushort* __restrict__ xh, const ushort* __restrict__ xl,
    const ushort* __restrict__ wfh, const ushort* __restrict__ wfl,
    const float* __restrict__ vb, float* __restrict__ vraw,
    float* __restrict__ part_v,
    const ushort* __restrict__ wqh, const ushort* __restrict__ wql,
    const float* __restrict__ bqk, float* __restrict__ qk1,
    float* __restrict__ part_qk)
{
  __shared__ ushort Bs[2 * 255 * 64];
  const int bx = blockIdx.x, nt = blockIdx.y, t = threadIdx.x;
  if (bx < 2)
    conv_mfma_body<8, 512>(Bs, xh, xl, wfh, wfl, vb, vraw, part_v, bx, nt, t);
  else
    conv_mfma_body<1, 32>(Bs, xh, xl, wqh, wql, bqk, qk1, part_qk, 0, nt, t);
}

template <int NMF, int OCS>
__global__ __launch_bounds__(256) void conv_v_mfma(
    const ushort* __restrict__ xh, const ushort* __restrict__ xl,
    const ushort* __restrict__ wh, const ushort* __restrict__ wl,
    const float* __restrict__ bias, float* __restrict__ y,
    float* __restrict__ part)
{
  __shared__ ushort Bs[2 * 255 * 64];
  conv_mfma_body<NMF, OCS>(Bs, xh, xl, wh, wl, bias, y, part,
                           blockIdx.x, blockIdx.y, threadIdx.x);
}

// ---------------------------------------------------------------------------
// finalize3 v3: 16 channels/block x 16 workers/channel, shfl reduce.
// ---------------------------------------------------------------------------
__global__ __launch_bounds__(256) void finalize3_kernel(
    const float* __restrict__ p1, int C1, int NT1, float* __restrict__ n1,
    const float* __restrict__ p2, int C2, int NT2, float* __restrict__ n2,
    const float* __restrict__ p3, int C3, int NT3, float* __restrict__ n3)
{
  const int t = threadIdx.x;
  const int chl = t >> 4, w = t & 15;
  const int g = blockIdx.x * 16 + chl;

  const float* part = nullptr; float* np = nullptr; int C = 0, NT = 0, c = 0;
  if (g < C1)                { part = p1; np = n1; C = C1; NT = NT1; c = g; }
  else if (g < C1 + C2)      { part = p2; np = n2; C = C2; NT = NT2; c = g - C1; }
  else if (g < C1 + C2 + C3) { part = p3; np = n3; C = C3; NT = NT3; c = g - C1 - C2; }

  float s = 0.f, ss = 0.f;
  if (part)
    for (int tile = w; tile < NT; tile += 16) {
      float2 v = *reinterpret_cast<const float2*>(&part[((size_t)tile * C + c) * 2]);
      s += v.x; ss += v.y;
    }
#pragma unroll
  for (int off = 1; off < 16; off <<= 1) {
    s  += __shfl_xor(s, off);
    ss += __shfl_xor(ss, off);
  }
  if (w == 0 && part) {
    float m = s * INV_VOX;
    float var = ss * INV_VOX - m * m;
    np[2 * c]     = m;
    np[2 * c + 1] = rsqrtf(var + EPSF);
  }
}

// ---------------------------------------------------------------------------
// qk_box v2 (unchanged).
// ---------------------------------------------------------------------------
__global__ __launch_bounds__(256) void qk_box_kernel(
    const float* __restrict__ qraw, const float* __restrict__ npq,
    const float* __restrict__ kraw, const float* __restrict__ npk,
    float* __restrict__ qkout)
{
  __shared__ float s[1000];
  __shared__ float ws2[800];
  const int j = blockIdx.y;
  const int tile = blockIdx.x;
  const int W0 = (tile & 7) * 8, H0 = ((tile >> 3) & 7) * 8, D0 = (tile >> 6) * 8;
  const int t = threadIdx.x;
  const int cbD = (D0 >> 1) - 1, cbH = (H0 >> 1) - 1, cbW = (W0 >> 1) - 1;
  const float2* npq2 = reinterpret_cast<const float2*>(npq);
  const float2* npk2 = reinterpret_cast<const float2*>(npk);

#pragma unroll
  for (int kk = 0; kk < 7; ++kk) {
    int f = t + kk * 256;
    if (f < 1728) {
      int par = f / 216, idx = f - par * 216;
      int dz = idx / 36, r2 = idx - dz * 36, hz = r2 / 6, wz = r2 - hz * 6;
      int pd = (par >> 2) & 1, ph = (par >> 1) & 1, pw = par & 1;
      int dzf = 2 * dz + pd - 1, hzf = 2 * hz + ph - 1, wzf = 2 * wz + pw - 1;
      if ((unsigned)dzf < 10u && (unsigned)hzf < 10u && (unsigned)wzf < 10u) {
        int cD = cbD + dz, cH = cbH + hz, cW = cbW + wz;
        float prod = 0.f;
        if ((unsigned)cD < 32u && (unsigned)cH < 32u && (unsigned)cW < 32u) {
          int cidx = cD * 1024 + cH * 32 + cW;
          int qc = j * 8 + par;
          float2 nq = npq2[qc];
          float2 nk = npk2[par];
          float qv = fmaxf((qraw[(size_t)qc * VOX + cidx] - nq.x) * nq.y, 0.f);
          float kv = fmaxf((kraw[(size_t)par * VOX + cidx] - nk.x) * nk.y, 0.f);
          prod = qv * kv;
        }
        s[dzf * 100 + hzf * 10 + wzf] = prod;
      }
    }
  }
  __syncthreads();
#pragma unroll
  for (int i = 0; i < 4; ++i) {
    int e = t + i * 256;
    if (e < 800) {
      int dz = e / 80, r2 = e - dz * 80, hz = r2 >> 3, wz1 = r2 & 7;
      int base = dz * 100 + hz * 10 + wz1;
      ws2[e] = s[base] + s[base + 1] + s[base + 2];
    }
  }
  __syncthreads();
#pragma unroll
  for (int rep = 0; rep < 2; ++rep) {
    int o = t + rep * 256;
    int wz = o & 7, hz = (o >> 3) & 7, dz = o >> 6;
    int wb = dz * 80 + hz * 8 + wz;
    float sum = 0.f;
#pragma unroll
    for (int a = 0; a < 3; ++a)
      sum += ws2[wb + a * 80] + ws2[wb + a * 80 + 8] + ws2[wb + a * 80 + 16];
    qkout[(size_t)j * 262144 + (D0 + dz) * 4096 + (H0 + hz) * 64 + (W0 + wz)] =
        sum * (1.f / 27.f);
  }
}

// ---------------------------------------------------------------------------
// einsum_box v12: coarse-voxel-per-thread. Thread t<216 owns coarse voxel
// idx=t of the 6^3 tile grid; per channel it loads 8 v values from global
// (once) and computes its <=8 fine qkv outputs from register qk weights.
// grid (4 = cHalf*2+ciHalf, 512 tiles), 256 thr, 16 channels/block.
// LDS: qkvs[1000] + wsum[800]. 2 barriers/iter (v10 ordering).
// ---------------------------------------------------------------------------
__global__ __launch_bounds__(256) void einsum_box_kernel(
    const float* __restrict__ vraw, const float* __restrict__ npv,
    const float* __restrict__ qk, float* __restrict__ out)
{
  __shared__ float qkvs[1000];
  __shared__ float wsum[800];

  const int c0 = (blockIdx.x & 1) * 32;
  const int ciBase = ((blockIdx.x >> 1) & 1) * 16;
  const int tile = blockIdx.y;
  const int W0 = (tile & 7) * 8, H0 = ((tile >> 3) & 7) * 8, D0 = (tile >> 6) * 8;
  const int t = threadIdx.x;
  const int cbD = (D0 >> 1) - 1, cbH = (H0 >> 1) - 1, cbW = (W0 >> 1) - 1;
  const float2* npv2 = reinterpret_cast<const float2*>(npv);

  // ---- coarse-voxel ownership + per-slot fine geometry/qk weights
  const bool act = t < 216;
  const int dz = t / 36, rr = t - dz * 36, hz = rr / 6, wz = rr - hz * 6;
  const int cD = cbD + dz, cH = cbH + hz, cW = cbW + wz;
  const bool cok = act && (unsigned)cD < 32u && (unsigned)cH < 32u &&
                   (unsigned)cW < 32u;
  const uint coff = cok ? (uint)(cD * 1024 + cH * 32 + cW) : 0u;

  int pos8[8]; float qr8[8][8];
#pragma unroll
  for (int s = 0; s < 8; ++s) {
    const int pd = s >> 2, ph = (s >> 1) & 1, pw = s & 1;
    const int dzf = 2 * dz - 1 + pd, hzf = 2 * hz - 1 + ph, wzf = 2 * wz - 1 + pw;
    const bool pok = act && (unsigned)dzf < 10u && (unsigned)hzf < 10u &&
                     (unsigned)wzf < 10u;
    pos8[s] = pok ? (dzf * 100 + hzf * 10 + wzf) : -1;
    const int D = 2 * cD + pd, H = 2 * cH + ph, W = 2 * cW + pw;
    const bool qok = pok && cok;
    const int fidx = qok ? (D * 4096 + H * 64 + W) : 0;
#pragma unroll
    for (int j = 0; j < 8; ++j)
      qr8[s][j] = qok ? qk[(size_t)j * 262144 + fidx] : 0.f;
  }

  // wsum / box slot precompute (v10-identical)
  int wb[4];
#pragma unroll
  for (int i = 0; i < 4; ++i) {
    int e = t + i * 256;
    int dzq = e / 80, r2 = e - dzq * 80, hzq = r2 >> 3, wz1 = r2 & 7;
    wb[i] = dzq * 100 + hzq * 10 + wz1;
  }
  int wb2[2]; float* op[2];
#pragma unroll
  for (int rep = 0; rep < 2; ++rep) {
    int o = t + rep * 256;
    int wzq = o & 7, hzq = (o >> 3) & 7, dzq = o >> 6;
    wb2[rep] = dzq * 80 + hzq * 8 + wzq;
    op[rep] = out + (size_t)c0 * 262144 +
              (D0 + dzq) * 4096 + (H0 + hzq) * 64 + (W0 + wzq);
  }

  for (int li = 0; li < 16; ++li) {
    const int ci = ciBase + li;
    const size_t cbase = (size_t)(c0 + ci) * 8 * VOX;
    // phase B: load 8 v (once), normalize, write this thread's fine outputs
    if (act) {
      float vn[8];
#pragma unroll
      for (int j = 0; j < 8; ++j) {
        float2 nv = npv2[(c0 + ci) * 8 + j];
        float raw = vraw[cbase + (size_t)j * VOX + coff];
        vn[j] = cok ? fmaxf((raw - nv.x) * nv.y, 0.f) : 0.f;
      }
#pragma unroll
      for (int s = 0; s < 8; ++s) {
        if (pos8[s] >= 0) {
          float val = qr8[s][0] * vn[0];
          val = fmaf(qr8[s][1], vn[1], val);
          val = fmaf(qr8[s][2], vn[2], val);
          val = fmaf(qr8[s][3], vn[3], val);
          val = fmaf(qr8[s][4], vn[4], val);
          val = fmaf(qr8[s][5], vn[5], val);
          val = fmaf(qr8[s][6], vn[6], val);
          val = fmaf(qr8[s][7], vn[7], val);
          qkvs[pos8[s]] = val;
        }
      }
    }
    __syncthreads();   // barrier 1: qkvs ready; prev iter's wsum reads done
    // W-pass
#pragma unroll
    for (int i = 0; i < 4; ++i) {
      if (i < 3 || t < 32) {
        int b = wb[i];
        wsum[t + i * 256] = qkvs[b] + qkvs[b + 1] + qkvs[b + 2];
      }
    }
    __syncthreads();   // barrier 2: wsum ready; next B may overwrite qkvs
    // H+D gather + store (reads wsum only; ordered vs next W by barrier 1)
#pragma unroll
    for (int rep = 0; rep < 2; ++rep) {
      float sum = 0.f;
#pragma unroll
      for (int a = 0; a < 3; ++a)
        sum += wsum[wb2[rep] + a * 80] + wsum[wb2[rep] + a * 80 + 8] +
               wsum[wb2[rep] + a * 80 + 16];
      op[rep][(size_t)ci << 18] = sum * (1.f / 27.f);
    }
  }
}

// ---------------------------------------------------------------------------
extern "C" void kernel_launch(void* const* d_in, const int* in_sizes, int n_in,
                              void* d_out, int out_size, void* d_ws, size_t ws_size,
                              hipStream_t stream)
{
  (void)in_sizes; (void)n_in; (void)out_size; (void)ws_size;
  const float* x   = (const float*)d_in[0];
  const float* q1w = (const float*)d_in[1];
  const float* q1b = (const float*)d_in[2];
  const float* q2w = (const float*)d_in[3];
  const float* q2b = (const float*)d_in[4];
  const float* k1w = (const float*)d_in[5];
  const float* k1b = (const float*)d_in[6];
  const float* k2w = (const float*)d_in[7];
  const float* k2b = (const float*)d_in[8];
  const float* vw  = (const float*)d_in[9];
  const float* vb  = (const float*)d_in[10];
  float* out = (float*)d_out;

  float* p = (float*)d_ws;
  float* vraw    = p; p += (size_t)512 * VOX;      // 64 MiB
  float* regionR = p; p += (size_t)96 * VOX;       // 12 MiB: qk1raw then y96
  float* qkbuf   = p; p += (size_t)8 * 262144;     // 8 MiB: xT / xT2 / qk
  float* part_v  = p; p += (size_t)512 * 512 * 2;
  float* part_qk = p; p += (size_t)512 * 32 * 2;
  float* part96  = p; p += (size_t)512 * 96 * 2;
  float* WfF     = p; p += (size_t)262144;
  float* WqF     = p; p += (size_t)16384;
  float* W2F     = p; p += (size_t)49152;
  float* np_qk1  = p; p += 64;
  float* np96    = p; p += 192;
  float* np_v    = p; p += 1024;
  float* bqk     = p; p += 32;
  float* b96     = p; p += 96;

  float* qk1raw = regionR;
  float* y96    = regionR;

  ushort* xT_hi = (ushort*)qkbuf;
  ushort* xT_lo = (ushort*)qkbuf + (size_t)32768 * 64;
  ushort* Wf_hi = (ushort*)WfF;
  ushort* Wf_lo = (ushort*)WfF + 262144;
  ushort* Wq_hi = (ushort*)WqF;
  ushort* Wq_lo = (ushort*)WqF + 16384;
  ushort* W2_hi = (ushort*)W2F;
  ushort* W2_lo = (ushort*)W2F + 49152;

  dim3 blk(256);
  prep_all_kernel<<<672, blk, 0, stream>>>(
      x, vw, q1w, q1b, k1w, k1b, q2w, q2b, k2w, k2b,
      xT_hi, xT_lo, Wf_hi, Wf_lo, Wq_hi, Wq_lo, bqk, W2_hi, W2_lo, b96);
  conv_fused_kernel<<<dim3(3, 256), blk, 0, stream>>>(
      xT_hi, xT_lo, Wf_hi, Wf_lo, vb, vraw, part_v,
      Wq_hi, Wq_lo, bqk, qk1raw, part_qk);
  finalize3_kernel<<<34, blk, 0, stream>>>(
      part_v, 512, 512, np_v,
      part_qk, 32, 512, np_qk1,
      nullptr, 0, 0, nullptr);
  xprep2_kernel<<<512, blk, 0, stream>>>(qk1raw, np_qk1, xT_hi, xT_lo);
  conv_v_mfma<3, 96><<<dim3(1, 256), blk, 0, stream>>>(
      xT_hi, xT_lo, W2_hi, W2_lo, b96, y96, part96);
  finalize3_kernel<<<6, blk, 0, stream>>>(
      part96, 96, 512, np96,
      nullptr, 0, 0, nullptr,
      nullptr, 0, 0, nullptr);
  qk_box_kernel<<<dim3(512, 8), blk, 0, stream>>>(
      y96, np96, y96 + (size_t)64 * VOX, np96 + 128, qkbuf);
  einsum_box_kernel<<<dim3(4, 512), blk, 0, stream>>>(
      vraw, np_v, qkbuf, out);
}

// Round 20
// 268.460 us; speedup vs baseline: 1.3989x; 1.0597x over previous
//
#include <hip/hip_runtime.h>
#include <hip/hip_bf16.h>

// QKV upsampling pipeline.
// R20: einsum reverted to v10 (best measured total, R16=278us). Conv staging
// switched to global_load_lds width=16: linear LDS dest + inverse-swizzled
// global source (pos=s>>3, cig=(s&7)^(pos&7)); OOB/tail -> 16B zpad.
// Bs padded to 64KiB so tail chunks land in dead pad. Read side unchanged.

constexpr int VOX = 32 * 32 * 32;
constexpr float INV_VOX = 1.0f / 32768.0f;
constexpr float EPSF = 1e-5f;

typedef __attribute__((ext_vector_type(8))) short s16x8;
typedef __attribute__((ext_vector_type(4))) float f32x4;

static __device__ __forceinline__ ushort bf16_bits(float v) {
  __hip_bfloat16 h = __float2bfloat16(v);
  return *reinterpret_cast<ushort*>(&h);
}

// ---------------------------------------------------------------------------
// Merged x-transpose (blocks 0-511) + weight prepack (blocks 512-671).
// Block 0 also zeroes the 16B zpad guard.
// ---------------------------------------------------------------------------
__global__ __launch_bounds__(256) void prep_all_kernel(
    const float* __restrict__ x,
    const float* __restrict__ vw,
    const float* __restrict__ q1w, const float* __restrict__ q1b,
    const float* __restrict__ k1w, const float* __restrict__ k1b,
    const float* __restrict__ q2w, const float* __restrict__ q2b,
    const float* __restrict__ k2w, const float* __restrict__ k2b,
    ushort* __restrict__ xh, ushort* __restrict__ xl,
    ushort* __restrict__ wfh, ushort* __restrict__ wfl,
    ushort* __restrict__ wqh, ushort* __restrict__ wql, float* __restrict__ bqk,
    ushort* __restrict__ w2h, ushort* __restrict__ w2l, float* __restrict__ b96,
    float* __restrict__ zpad)
{
  __shared__ float ts[64][65];
  const int t = threadIdx.x;
  if ((int)blockIdx.x < 512) {
    if (blockIdx.x == 0 && t == 0)
      *reinterpret_cast<uint4*>(zpad) = make_uint4(0u, 0u, 0u, 0u);
    const int vox0 = blockIdx.x * 64;
#pragma unroll
    for (int i = 0; i < 16; ++i) {
      int e = i * 256 + t;
      int ci = e >> 6, vl = e & 63;
      ts[ci][vl] = x[(size_t)ci * VOX + vox0 + vl];
    }
    __syncthreads();
    const int vl = t >> 2, cig = t & 3;
    uint h[8], l[8];
#pragma unroll
    for (int p = 0; p < 8; ++p) {
      float v0 = ts[cig * 16 + 2 * p][vl];
      float v1 = ts[cig * 16 + 2 * p + 1][vl];
      ushort h0 = bf16_bits(v0), h1 = bf16_bits(v1);
      float r0 = v0 - __bfloat162float(*reinterpret_cast<__hip_bfloat16*>(&h0));
      float r1 = v1 - __bfloat162float(*reinterpret_cast<__hip_bfloat16*>(&h1));
      h[p] = (uint)h0 | ((uint)h1 << 16);
      l[p] = (uint)bf16_bits(r0) | ((uint)bf16_bits(r1) << 16);
    }
    size_t base = (size_t)(vox0 + vl) * 64 + cig * 16;
    *reinterpret_cast<uint4*>(xh + base)     = make_uint4(h[0], h[1], h[2], h[3]);
    *reinterpret_cast<uint4*>(xh + base + 8) = make_uint4(h[4], h[5], h[6], h[7]);
    *reinterpret_cast<uint4*>(xl + base)     = make_uint4(l[0], l[1], l[2], l[3]);
    *reinterpret_cast<uint4*>(xl + base + 8) = make_uint4(l[4], l[5], l[6], l[7]);
    return;
  }
  const int bid = blockIdx.x - 512;
  if (bid < 128) {
    int tid = bid * 256 + t;
    int oc = tid & 511, g = (tid >> 9) & 3, khalf = (tid >> 11) & 1, tap = tid >> 12;
    uint h[4], l[4];
#pragma unroll
    for (int p = 0; p < 4; ++p) {
      int ci0 = khalf * 32 + g * 8 + 2 * p;
      float v0 = vw[oc * 512 + ci0 * 8 + tap];
      float v1 = vw[oc * 512 + (ci0 + 1) * 8 + tap];
      ushort h0 = bf16_bits(v0), h1 = bf16_bits(v1);
      float r0 = v0 - __bfloat162float(*reinterpret_cast<__hip_bfloat16*>(&h0));
      float r1 = v1 - __bfloat162float(*reinterpret_cast<__hip_bfloat16*>(&h1));
      h[p] = (uint)h0 | ((uint)h1 << 16);
      l[p] = (uint)bf16_bits(r0) | ((uint)bf16_bits(r1) << 16);
    }
    size_t base = (size_t)tid * 8;
    *reinterpret_cast<uint4*>(wfh + base) = make_uint4(h[0], h[1], h[2], h[3]);
    *reinterpret_cast<uint4*>(wfl + base) = make_uint4(l[0], l[1], l[2], l[3]);
  } else if (bid < 136) {
    int tid = (bid - 128) * 256 + t;
    if (tid < 32) bqk[tid] = tid < 16 ? q1b[tid] : k1b[tid - 16];
    int oc = tid & 31, g = (tid >> 5) & 3, khalf = (tid >> 7) & 1, tap = tid >> 8;
    const float* src = oc < 16 ? q1w + oc * 512 : k1w + (oc - 16) * 512;
    uint h[4], l[4];
#pragma unroll
    for (int p = 0; p < 4; ++p) {
      int ci0 = khalf * 32 + g * 8 + 2 * p;
      float v0 = src[ci0 * 8 + tap];
      float v1 = src[(ci0 + 1) * 8 + tap];
      ushort h0 = bf16_bits(v0), h1 = bf16_bits(v1);
      float r0 = v0 - __bfloat162float(*reinterpret_cast<__hip_bfloat16*>(&h0));
      float r1 = v1 - __bfloat162float(*reinterpret_cast<__hip_bfloat16*>(&h1));
      h[p] = (uint)h0 | ((uint)h1 << 16);
      l[p] = (uint)bf16_bits(r0) | ((uint)bf16_bits(r1) << 16);
    }
    size_t base = (size_t)tid * 8;
    *reinterpret_cast<uint4*>(wqh + base) = make_uint4(h[0], h[1], h[2], h[3]);
    *reinterpret_cast<uint4*>(wql + base) = make_uint4(l[0], l[1], l[2], l[3]);
  } else {
    int tid = (bid - 136) * 256 + t;
    if (tid < 96) b96[tid] = tid < 64 ? q2b[tid] : (tid < 72 ? k2b[tid - 64] : 0.f);
    int oc = tid % 96, g = (tid / 96) & 3, kslot = tid / 384;
    int khalf = kslot & 1, tap = kslot >> 1;
    uint h[4], l[4];
#pragma unroll
    for (int p = 0; p < 4; ++p) {
      float v[2];
#pragma unroll
      for (int q = 0; q < 2; ++q) {
        int ci = khalf * 32 + g * 8 + 2 * p + q;
        float w = 0.f;
        if (ci < 16) { if (oc < 64) w = q2w[(oc * 16 + ci) * 8 + tap]; }
        else if (ci < 32) {
          if (oc >= 64 && oc < 72) w = k2w[((oc - 64) * 16 + (ci - 16)) * 8 + tap];
        }
        v[q] = w;
      }
      ushort h0 = bf16_bits(v[0]), h1 = bf16_bits(v[1]);
      float r0 = v[0] - __bfloat162float(*reinterpret_cast<__hip_bfloat16*>(&h0));
      float r1 = v[1] - __bfloat162float(*reinterpret_cast<__hip_bfloat16*>(&h1));
      h[p] = (uint)h0 | ((uint)h1 << 16);
      l[p] = (uint)bf16_bits(r0) | ((uint)bf16_bits(r1) << 16);
    }
    size_t base = (size_t)tid * 8;
    *reinterpret_cast<uint4*>(w2h + base) = make_uint4(h[0], h[1], h[2], h[3]);
    *reinterpret_cast<uint4*>(w2l + base) = make_uint4(l[0], l[1], l[2], l[3]);
  }
}

// ---------------------------------------------------------------------------
// Normalize q1/k1 -> [vox][64] bf16 hi/lo, ci 32..63 zeroed (unchanged).
// ---------------------------------------------------------------------------
__global__ __launch_bounds__(256) void xprep2_kernel(
    const float* __restrict__ qk1, const float* __restrict__ np,
    ushort* __restrict__ xh, ushort* __restrict__ xl)
{
  __shared__ float ts[32][65];
  const int t = threadIdx.x;
  const int vox0 = blockIdx.x * 64;
#pragma unroll
  for (int i = 0; i < 8; ++i) {
    int e = i * 256 + t;
    int ci = e >> 6, vl = e & 63;
    float m = np[2 * ci], rs = np[2 * ci + 1];
    float v = qk1[(size_t)ci * VOX + vox0 + vl];
    ts[ci][vl] = fmaxf((v - m) * rs, 0.f);
  }
  __syncthreads();
  const int vl = t >> 2, cig = t & 3;
  uint h[8], l[8];
#pragma unroll
  for (int p = 0; p < 8; ++p) {
    if (cig < 2) {
      float v0 = ts[cig * 16 + 2 * p][vl];
      float v1 = ts[cig * 16 + 2 * p + 1][vl];
      ushort h0 = bf16_bits(v0), h1 = bf16_bits(v1);
      float r0 = v0 - __bfloat162float(*reinterpret_cast<__hip_bfloat16*>(&h0));
      float r1 = v1 - __bfloat162float(*reinterpret_cast<__hip_bfloat16*>(&h1));
      h[p] = (uint)h0 | ((uint)h1 << 16);
      l[p] = (uint)bf16_bits(r0) | ((uint)bf16_bits(r1) << 16);
    } else { h[p] = 0u; l[p] = 0u; }
  }
  size_t base = (size_t)(vox0 + vl) * 64 + cig * 16;
  *reinterpret_cast<uint4*>(xh + base)     = make_uint4(h[0], h[1], h[2], h[3]);
  *reinterpret_cast<uint4*>(xh + base + 8) = make_uint4(h[4], h[5], h[6], h[7]);
  *reinterpret_cast<uint4*>(xl + base)     = make_uint4(l[0], l[1], l[2], l[3]);
  *reinterpret_cast<uint4*>(xl + base + 8) = make_uint4(l[4], l[5], l[6], l[7]);
}

// ---------------------------------------------------------------------------
// MFMA conv body. Staging via global_load_lds (linear LDS dest, inverse-
// swizzled global source). Read side unchanged (swizzled).
// ---------------------------------------------------------------------------
template <int NMF, int OCS>
__device__ __forceinline__ void conv_mfma_body(
    ushort* Bs,
    const ushort* __restrict__ xh, const ushort* __restrict__ xl,
    const ushort* __restrict__ wh, const ushort* __restrict__ wl,
    const float* __restrict__ bias, float* __restrict__ y,
    float* __restrict__ part, const ushort* __restrict__ zpad,
    int bx, int nt, int t)
{
  const int wave = t >> 6, lane = t & 63;
  const int wm = wave >> 1, wn = wave & 1;
  const int g = lane >> 4, ww = lane & 15;
  const int m0 = bx * (NMF * 32);
  const int td = nt >> 4, th = (nt >> 1) & 7, tw = nt & 1;
  const int d0 = td * 2, h0 = th * 4, w0 = tw * 16;

  char* BsB = reinterpret_cast<char*>(Bs);
#pragma unroll
  for (int i = 0; i < 16; ++i) {
    const int s = i * 256 + t;                       // chunk 0..4095
    const int split = (s >= 2040 && s < 4080) ? 1 : 0;
    const int s2 = s - split * 2040;
    const bool tail = s >= 4080;
    const int pos = s2 >> 3;
    const int cig = (s2 & 7) ^ (pos & 7);
    const int dz = pos / 85, rem = pos - dz * 85;
    const int hz = rem / 17, wz = rem - hz * 17;
    const int d = d0 + dz, h = h0 + hz, w = w0 + wz;
    const bool ok = !tail && d < 32 && h < 32 && w < 32;
    const ushort* src = split ? xl : xh;
    const ushort* gp =
        ok ? (src + (size_t)(d * 1024 + h * 32 + w) * 64 + cig * 8) : zpad;
    __builtin_amdgcn_global_load_lds(
        (const __attribute__((address_space(1))) void*)gp,
        (__attribute__((address_space(3))) void*)(BsB + s * 16), 16, 0, 0);
  }
  __syncthreads();

  const int ocl = m0 + wm * (NMF * 16) + ww;
  f32x4 acc[NMF][4];
#pragma unroll
  for (int mf = 0; mf < NMF; ++mf)
#pragma unroll
    for (int hh = 0; hh < 4; ++hh) acc[mf][hh] = (f32x4){0.f, 0.f, 0.f, 0.f};

  for (int tap = 0; tap < 8; ++tap) {
    const int kd = tap >> 2, kh = (tap >> 1) & 1, kw = tap & 1;
#pragma unroll
    for (int khalf = 0; khalf < 2; ++khalf) {
      const size_t abase = ((size_t)((tap * 2 + khalf) * 4 + g) * OCS + ocl) * 8;
      s16x8 Ah[NMF], Al[NMF];
#pragma unroll
      for (int mf = 0; mf < NMF; ++mf) {
        Ah[mf] = *reinterpret_cast<const s16x8*>(wh + abase + mf * 16 * 8);
        Al[mf] = *reinterpret_cast<const s16x8*>(wl + abase + mf * 16 * 8);
      }
      const int srow = ((wn + kd) * 5 + kh) * 17 + kw;
#pragma unroll
      for (int hh = 0; hh < 4; ++hh) {
        int pos = srow + hh * 17 + ww;
        int baddr = (pos << 7) + khalf * 64 + g * 16;
        baddr ^= (pos & 7) << 4;
        const char* bp = reinterpret_cast<const char*>(Bs) + baddr;
        s16x8 Bh = *reinterpret_cast<const s16x8*>(bp);
        s16x8 Bl = *reinterpret_cast<const s16x8*>(bp + 32640);
#pragma unroll
        for (int mf = 0; mf < NMF; ++mf) {
          acc[mf][hh] = __builtin_amdgcn_mfma_f32_16x16x32_bf16(
              Ah[mf], Bh, acc[mf][hh], 0, 0, 0);
          acc[mf][hh] = __builtin_amdgcn_mfma_f32_16x16x32_bf16(
              Al[mf], Bh, acc[mf][hh], 0, 0, 0);
          acc[mf][hh] = __builtin_amdgcn_mfma_f32_16x16x32_bf16(
              Ah[mf], Bl, acc[mf][hh], 0, 0, 0);
        }
      }
    }
  }

  float bs[NMF][4];
#pragma unroll
  for (int mf = 0; mf < NMF; ++mf)
#pragma unroll
    for (int reg = 0; reg < 4; ++reg)
      bs[mf][reg] = bias[m0 + wm * (NMF * 16) + mf * 16 + g * 4 + reg];

  float ssum[NMF][4], ssq[NMF][4];
#pragma unroll
  for (int mf = 0; mf < NMF; ++mf)
#pragma unroll
    for (int reg = 0; reg < 4; ++reg) { ssum[mf][reg] = 0.f; ssq[mf][reg] = 0.f; }

#pragma unroll
  for (int mf = 0; mf < NMF; ++mf) {
#pragma unroll
    for (int hh = 0; hh < 4; ++hh) {
      int vox = (d0 + wn) * 1024 + (h0 + hh) * 32 + w0 + ww;
#pragma unroll
      for (int reg = 0; reg < 4; ++reg) {
        float v = acc[mf][hh][reg] + bs[mf][reg];
        int oc = m0 + wm * (NMF * 16) + mf * 16 + g * 4 + reg;
        y[(size_t)oc * VOX + vox] = v;
        ssum[mf][reg] += v;
        ssq[mf][reg] += v * v;
      }
    }
  }
#pragma unroll
  for (int mf = 0; mf < NMF; ++mf)
#pragma unroll
    for (int reg = 0; reg < 4; ++reg)
#pragma unroll
      for (int off = 1; off < 16; off <<= 1) {
        ssum[mf][reg] += __shfl_xor(ssum[mf][reg], off);
        ssq[mf][reg]  += __shfl_xor(ssq[mf][reg], off);
      }
  if ((lane & 15) == 0) {
    float* pp = part + (size_t)(nt * 2 + wn) * (OCS * 2);
#pragma unroll
    for (int mf = 0; mf < NMF; ++mf)
#pragma unroll
      for (int reg = 0; reg < 4; ++reg) {
        int oc = m0 + wm * (NMF * 16) + mf * 16 + g * 4 + reg;
        pp[oc * 2]     = ssum[mf][reg];
        pp[oc * 2 + 1] = ssq[mf][reg];
      }
  }
}

__global__ __launch_bounds__(256) void conv_fused_kernel(
    const ushort* __restrict__ xh, const ushort* __restrict__ xl,
    const ushort* __restrict__ wfh, const ushort* __restrict__ wfl,
    const float* __restrict__ vb, float* __restrict__ vraw,
    float* __restrict__ part_v,
    const ushort* __restrict__ wqh, const ushort* __restrict__ wql,
    const float* __restrict__ bqk, float* __restrict__ qk1,
    float* __restrict__ part_qk, const ushort* __restrict__ zpad)
{
  __shared__ ushort Bs[2 * 256 * 64];   // 64 KiB (last 256B = dead pad)
  const int bx = blockIdx.x, nt = blockIdx.y, t = threadIdx.x;
  if (bx < 2)
    conv_mfma_body<8, 512>(Bs, xh, xl, wfh, wfl, vb, vraw, part_v, zpad,
                           bx, nt, t);
  else
    conv_mfma_body<1, 32>(Bs, xh, xl, wqh, wql, bqk, qk1, part_qk, zpad,
                          0, nt, t);
}

template <int NMF, int OCS>
__global__ __launch_bounds__(256) void conv_v_mfma(
    const ushort* __restrict__ xh, const ushort* __restrict__ xl,
    const ushort* __restrict__ wh, const ushort* __restrict__ wl,
    const float* __restrict__ bias, float* __restrict__ y,
    float* __restrict__ part, const ushort* __restrict__ zpad)
{
  __shared__ ushort Bs[2 * 256 * 64];
  conv_mfma_body<NMF, OCS>(Bs, xh, xl, wh, wl, bias, y, part, zpad,
                           blockIdx.x, blockIdx.y, threadIdx.x);
}

// ---------------------------------------------------------------------------
// finalize3 v3: 16 channels/block x 16 workers/channel, shfl reduce.
// ---------------------------------------------------------------------------
__global__ __launch_bounds__(256) void finalize3_kernel(
    const float* __restrict__ p1, int C1, int NT1, float* __restrict__ n1,
    const float* __restrict__ p2, int C2, int NT2, float* __restrict__ n2,
    const float* __restrict__ p3, int C3, int NT3, float* __restrict__ n3)
{
  const int t = threadIdx.x;
  const int chl = t >> 4, w = t & 15;
  const int g = blockIdx.x * 16 + chl;

  const float* part = nullptr; float* np = nullptr; int C = 0, NT = 0, c = 0;
  if (g < C1)                { part = p1; np = n1; C = C1; NT = NT1; c = g; }
  else if (g < C1 + C2)      { part = p2; np = n2; C = C2; NT = NT2; c = g - C1; }
  else if (g < C1 + C2 + C3) { part = p3; np = n3; C = C3; NT = NT3; c = g - C1 - C2; }

  float s = 0.f, ss = 0.f;
  if (part)
    for (int tile = w; tile < NT; tile += 16) {
      float2 v = *reinterpret_cast<const float2*>(&part[((size_t)tile * C + c) * 2]);
      s += v.x; ss += v.y;
    }
#pragma unroll
  for (int off = 1; off < 16; off <<= 1) {
    s  += __shfl_xor(s, off);
    ss += __shfl_xor(ss, off);
  }
  if (w == 0 && part) {
    float m = s * INV_VOX;
    float var = ss * INV_VOX - m * m;
    np[2 * c]     = m;
    np[2 * c + 1] = rsqrtf(var + EPSF);
  }
}

// ---------------------------------------------------------------------------
// qk_box v2 (unchanged).
// ---------------------------------------------------------------------------
__global__ __launch_bounds__(256) void qk_box_kernel(
    const float* __restrict__ qraw, const float* __restrict__ npq,
    const float* __restrict__ kraw, const float* __restrict__ npk,
    float* __restrict__ qkout)
{
  __shared__ float s[1000];
  __shared__ float ws2[800];
  const int j = blockIdx.y;
  const int tile = blockIdx.x;
  const int W0 = (tile & 7) * 8, H0 = ((tile >> 3) & 7) * 8, D0 = (tile >> 6) * 8;
  const int t = threadIdx.x;
  const int cbD = (D0 >> 1) - 1, cbH = (H0 >> 1) - 1, cbW = (W0 >> 1) - 1;
  const float2* npq2 = reinterpret_cast<const float2*>(npq);
  const float2* npk2 = reinterpret_cast<const float2*>(npk);

#pragma unroll
  for (int kk = 0; kk < 7; ++kk) {
    int f = t + kk * 256;
    if (f < 1728) {
      int par = f / 216, idx = f - par * 216;
      int dz = idx / 36, r2 = idx - dz * 36, hz = r2 / 6, wz = r2 - hz * 6;
      int pd = (par >> 2) & 1, ph = (par >> 1) & 1, pw = par & 1;
      int dzf = 2 * dz + pd - 1, hzf = 2 * hz + ph - 1, wzf = 2 * wz + pw - 1;
      if ((unsigned)dzf < 10u && (unsigned)hzf < 10u && (unsigned)wzf < 10u) {
        int cD = cbD + dz, cH = cbH + hz, cW = cbW + wz;
        float prod = 0.f;
        if ((unsigned)cD < 32u && (unsigned)cH < 32u && (unsigned)cW < 32u) {
          int cidx = cD * 1024 + cH * 32 + cW;
          int qc = j * 8 + par;
          float2 nq = npq2[qc];
          float2 nk = npk2[par];
          float qv = fmaxf((qraw[(size_t)qc * VOX + cidx] - nq.x) * nq.y, 0.f);
          float kv = fmaxf((kraw[(size_t)par * VOX + cidx] - nk.x) * nk.y, 0.f);
          prod = qv * kv;
        }
        s[dzf * 100 + hzf * 10 + wzf] = prod;
      }
    }
  }
  __syncthreads();
#pragma unroll
  for (int i = 0; i < 4; ++i) {
    int e = t + i * 256;
    if (e < 800) {
      int dz = e / 80, r2 = e - dz * 80, hz = r2 >> 3, wz1 = r2 & 7;
      int base = dz * 100 + hz * 10 + wz1;
      ws2[e] = s[base] + s[base + 1] + s[base + 2];
    }
  }
  __syncthreads();
#pragma unroll
  for (int rep = 0; rep < 2; ++rep) {
    int o = t + rep * 256;
    int wz = o & 7, hz = (o >> 3) & 7, dz = o >> 6;
    int wb = dz * 80 + hz * 8 + wz;
    float sum = 0.f;
#pragma unroll
    for (int a = 0; a < 3; ++a)
      sum += ws2[wb + a * 80] + ws2[wb + a * 80 + 8] + ws2[wb + a * 80 + 16];
    qkout[(size_t)j * 262144 + (D0 + dz) * 4096 + (H0 + hz) * 64 + (W0 + wz)] =
        sum * (1.f / 27.f);
  }
}

// ---------------------------------------------------------------------------
// einsum_box v10 (R16 best measured): v7 structure + ci-loop split in 2.
// grid (4 = cHalf*2+ciHalf, 512 tiles), 256 thr, 16 channels/block.
// ---------------------------------------------------------------------------
__global__ __launch_bounds__(256) void einsum_box_kernel(
    const float* __restrict__ vraw, const float* __restrict__ npv,
    const float* __restrict__ qk, float* __restrict__ out)
{
  __shared__ char vs_raw[2][6912];
  __shared__ float qkvs[1000];
  __shared__ float wsum[800];

  const int c0 = (blockIdx.x & 1) * 32;
  const int ciBase = ((blockIdx.x >> 1) & 1) * 16;
  const int tile = blockIdx.y;
  const int W0 = (tile & 7) * 8, H0 = ((tile >> 3) & 7) * 8, D0 = (tile >> 6) * 8;
  const int t = threadIdx.x;
  const int cbD = (D0 >> 1) - 1, cbH = (H0 >> 1) - 1, cbW = (W0 >> 1) - 1;
  const float2* npv2 = reinterpret_cast<const float2*>(npv);

  uint soff[7]; int sbyte[7]; int snidx[7]; bool svalid[7];
#pragma unroll
  for (int k = 0; k < 7; ++k) {
    int f = t + k * 256;
    int j = f / 216, idx = f - j * 216;
    int dz = idx / 36, r2 = idx - dz * 36, hz = r2 / 6, wz = r2 - hz * 6;
    int cD = cbD + dz, cH = cbH + hz, cW = cbW + wz;
    bool vld = (f < 1728) && (unsigned)cD < 32u && (unsigned)cH < 32u &&
               (unsigned)cW < 32u;
    svalid[k] = vld;
    soff[k] = vld ? (uint)((c0 * 8 + j) * VOX + cD * 1024 + cH * 32 + cW) : 0u;
    snidx[k] = (f < 1728) ? (c0 * 8 + j) : 0;
    int byte = idx * 32 + (j >> 2) * 16 + (j & 3) * 4;
    sbyte[k] = byte ^ (((idx >> 2) & 7) << 4);
  }

  int vbyte[4]; float qr[4][8];
#pragma unroll
  for (int i = 0; i < 4; ++i) {
    int pos = t + i * 256;
    vbyte[i] = 0;
#pragma unroll
    for (int j = 0; j < 8; ++j) qr[i][j] = 0.f;
    if (pos < 1000) {
      int dz = pos / 100, rem = pos - dz * 100, hz = rem / 10, wz = rem - hz * 10;
      int D = D0 - 1 + dz, H = H0 - 1 + hz, W = W0 - 1 + wz;
      if ((unsigned)D < 64u && (unsigned)H < 64u && (unsigned)W < 64u) {
        int fidx = D * 4096 + H * 64 + W;
#pragma unroll
        for (int j = 0; j < 8; ++j)
          qr[i][j] = qk[(size_t)j * 262144 + fidx];
        int vidx = ((D >> 1) - cbD) * 36 + ((H >> 1) - cbH) * 6 + ((W >> 1) - cbW);
        vbyte[i] = (vidx * 32) ^ (((vidx >> 2) & 7) << 4);
      }
    }
  }

  int wb[4];
#pragma unroll
  for (int i = 0; i < 4; ++i) {
    int e = t + i * 256;
    int dz = e / 80, r2 = e - dz * 80, hz = r2 >> 3, wz1 = r2 & 7;
    wb[i] = dz * 100 + hz * 10 + wz1;
  }
  int wb2[2]; float* op[2];
#pragma unroll
  for (int rep = 0; rep < 2; ++rep) {
    int o = t + rep * 256;
    int wz = o & 7, hz = (o >> 3) & 7, dz = o >> 6;
    wb2[rep] = dz * 80 + hz * 8 + wz;
    op[rep] = out + (size_t)c0 * 262144 +
              (D0 + dz) * 4096 + (H0 + hz) * 64 + (W0 + wz);
  }

  float pre[7];
  auto fetchv = [&](int ci) {
    const uint cio = (uint)(ci * 8 * VOX);
    const int cin8 = ci * 8;
#pragma unroll
    for (int k = 0; k < 7; ++k) {
      if (k < 6 || t < 192) {
        float2 mr = npv2[snidx[k] + cin8];
        float raw = vraw[soff[k] + cio];
        pre[k] = svalid[k] ? fmaxf((raw - mr.x) * mr.y, 0.f) : 0.f;
      }
    }
  };

  fetchv(ciBase);
#pragma unroll
  for (int k = 0; k < 7; ++k)
    if (k < 6 || t < 192)
      *reinterpret_cast<float*>(vs_raw[0] + sbyte[k]) = pre[k];
  fetchv(ciBase + 1);
  __syncthreads();

  for (int li = 0; li < 16; ++li) {
    const int ci = ciBase + li;
    const int cbuf = li & 1;
    if (li < 15) {
#pragma unroll
      for (int k = 0; k < 7; ++k)
        if (k < 6 || t < 192)
          *reinterpret_cast<float*>(vs_raw[cbuf ^ 1] + sbyte[k]) = pre[k];
      if (li < 14) fetchv(ci + 2);
    }
#pragma unroll
    for (int i = 0; i < 4; ++i) {
      int pos = t + i * 256;
      if (pos < 1000) {
        const char* vb0 = vs_raw[cbuf];
        float4 va = *reinterpret_cast<const float4*>(vb0 + vbyte[i]);
        float4 vb = *reinterpret_cast<const float4*>(vb0 + (vbyte[i] ^ 16));
        float val = qr[i][0] * va.x;
        val = fmaf(qr[i][1], va.y, val);
        val = fmaf(qr[i][2], va.z, val);
        val = fmaf(qr[i][3], va.w, val);
        val = fmaf(qr[i][4], vb.x, val);
        val = fmaf(qr[i][5], vb.y, val);
        val = fmaf(qr[i][6], vb.z, val);
        val = fmaf(qr[i][7], vb.w, val);
        qkvs[pos] = val;
      }
    }
    __syncthreads();
#pragma unroll
    for (int i = 0; i < 4; ++i) {
      if (i < 3 || t < 32) {
        int b = wb[i];
        wsum[t + i * 256] = qkvs[b] + qkvs[b + 1] + qkvs[b + 2];
      }
    }
    __syncthreads();
#pragma unroll
    for (int rep = 0; rep < 2; ++rep) {
      float sum = 0.f;
#pragma unroll
      for (int a = 0; a < 3; ++a)
        sum += wsum[wb2[rep] + a * 80] + wsum[wb2[rep] + a * 80 + 8] +
               wsum[wb2[rep] + a * 80 + 16];
      op[rep][(size_t)ci << 18] = sum * (1.f / 27.f);
    }
  }
}

// ---------------------------------------------------------------------------
extern "C" void kernel_launch(void* const* d_in, const int* in_sizes, int n_in,
                              void* d_out, int out_size, void* d_ws, size_t ws_size,
                              hipStream_t stream)
{
  (void)in_sizes; (void)n_in; (void)out_size; (void)ws_size;
  const float* x   = (const float*)d_in[0];
  const float* q1w = (const float*)d_in[1];
  const float* q1b = (const float*)d_in[2];
  const float* q2w = (const float*)d_in[3];
  const float* q2b = (const float*)d_in[4];
  const float* k1w = (const float*)d_in[5];
  const float* k1b = (const float*)d_in[6];
  const float* k2w = (const float*)d_in[7];
  const float* k2b = (const float*)d_in[8];
  const float* vw  = (const float*)d_in[9];
  const float* vb  = (const float*)d_in[10];
  float* out = (float*)d_out;

  float* p = (float*)d_ws;
  float* vraw    = p; p += (size_t)512 * VOX;      // 64 MiB
  float* regionR = p; p += (size_t)96 * VOX;       // 12 MiB: qk1raw then y96
  float* qkbuf   = p; p += (size_t)8 * 262144;     // 8 MiB: xT / xT2 / qk
  float* part_v  = p; p += (size_t)512 * 512 * 2;
  float* part_qk = p; p += (size_t)512 * 32 * 2;
  float* part96  = p; p += (size_t)512 * 96 * 2;
  float* WfF     = p; p += (size_t)262144;
  float* WqF     = p; p += (size_t)16384;
  float* W2F     = p; p += (size_t)49152;
  float* np_qk1  = p; p += 64;
  float* np96    = p; p += 192;
  float* np_v    = p; p += 1024;
  float* bqk     = p; p += 32;
  float* b96     = p; p += 96;
  float* zpadf   = p; p += 4;                      // 16B zero guard

  float* qk1raw = regionR;
  float* y96    = regionR;

  ushort* xT_hi = (ushort*)qkbuf;
  ushort* xT_lo = (ushort*)qkbuf + (size_t)32768 * 64;
  ushort* Wf_hi = (ushort*)WfF;
  ushort* Wf_lo = (ushort*)WfF + 262144;
  ushort* Wq_hi = (ushort*)WqF;
  ushort* Wq_lo = (ushort*)WqF + 16384;
  ushort* W2_hi = (ushort*)W2F;
  ushort* W2_lo = (ushort*)W2F + 49152;
  const ushort* zpad = (const ushort*)zpadf;

  dim3 blk(256);
  prep_all_kernel<<<672, blk, 0, stream>>>(
      x, vw, q1w, q1b, k1w, k1b, q2w, q2b, k2w, k2b,
      xT_hi, xT_lo, Wf_hi, Wf_lo, Wq_hi, Wq_lo, bqk, W2_hi, W2_lo, b96, zpadf);
  conv_fused_kernel<<<dim3(3, 256), blk, 0, stream>>>(
      xT_hi, xT_lo, Wf_hi, Wf_lo, vb, vraw, part_v,
      Wq_hi, Wq_lo, bqk, qk1raw, part_qk, zpad);
  finalize3_kernel<<<34, blk, 0, stream>>>(
      part_v, 512, 512, np_v,
      part_qk, 32, 512, np_qk1,
      nullptr, 0, 0, nullptr);
  xprep2_kernel<<<512, blk, 0, stream>>>(qk1raw, np_qk1, xT_hi, xT_lo);
  conv_v_mfma<3, 96><<<dim3(1, 256), blk, 0, stream>>>(
      xT_hi, xT_lo, W2_hi, W2_lo, b96, y96, part96, zpad);
  finalize3_kernel<<<6, blk, 0, stream>>>(
      part96, 96, 512, np96,
      nullptr, 0, 0, nullptr,
      nullptr, 0, 0, nullptr);
  qk_box_kernel<<<dim3(512, 8), blk, 0, stream>>>(
      y96, np96, y96 + (size_t)64 * VOX, np96 + 128, qkbuf);
  einsum_box_kernel<<<dim3(4, 512), blk, 0, stream>>>(
      vraw, np_v, qkbuf, out);
}

// Round 21
// 265.389 us; speedup vs baseline: 1.4151x; 1.0116x over previous
//
#include <hip/hip_runtime.h>
#include <hip/hip_bf16.h>

// QKV upsampling pipeline.
// R21: einsum v10 + XCD-locality swizzle (T1): flat grid 2048, bijective
// remap (xcd=bid&7, tile=xcd*64+(bid>>5), sub=(bid>>3)&3) puts all 4 sibling
// blocks of a tile on ONE XCD so the qk halo is fetched into one L2, not 4.
// Everything else identical to R20 (268.5us best).

constexpr int VOX = 32 * 32 * 32;
constexpr float INV_VOX = 1.0f / 32768.0f;
constexpr float EPSF = 1e-5f;

typedef __attribute__((ext_vector_type(8))) short s16x8;
typedef __attribute__((ext_vector_type(4))) float f32x4;

static __device__ __forceinline__ ushort bf16_bits(float v) {
  __hip_bfloat16 h = __float2bfloat16(v);
  return *reinterpret_cast<ushort*>(&h);
}

// ---------------------------------------------------------------------------
// Merged x-transpose (blocks 0-511) + weight prepack (blocks 512-671).
// Block 0 also zeroes the 16B zpad guard.
// ---------------------------------------------------------------------------
__global__ __launch_bounds__(256) void prep_all_kernel(
    const float* __restrict__ x,
    const float* __restrict__ vw,
    const float* __restrict__ q1w, const float* __restrict__ q1b,
    const float* __restrict__ k1w, const float* __restrict__ k1b,
    const float* __restrict__ q2w, const float* __restrict__ q2b,
    const float* __restrict__ k2w, const float* __restrict__ k2b,
    ushort* __restrict__ xh, ushort* __restrict__ xl,
    ushort* __restrict__ wfh, ushort* __restrict__ wfl,
    ushort* __restrict__ wqh, ushort* __restrict__ wql, float* __restrict__ bqk,
    ushort* __restrict__ w2h, ushort* __restrict__ w2l, float* __restrict__ b96,
    float* __restrict__ zpad)
{
  __shared__ float ts[64][65];
  const int t = threadIdx.x;
  if ((int)blockIdx.x < 512) {
    if (blockIdx.x == 0 && t == 0)
      *reinterpret_cast<uint4*>(zpad) = make_uint4(0u, 0u, 0u, 0u);
    const int vox0 = blockIdx.x * 64;
#pragma unroll
    for (int i = 0; i < 16; ++i) {
      int e = i * 256 + t;
      int ci = e >> 6, vl = e & 63;
      ts[ci][vl] = x[(size_t)ci * VOX + vox0 + vl];
    }
    __syncthreads();
    const int vl = t >> 2, cig = t & 3;
    uint h[8], l[8];
#pragma unroll
    for (int p = 0; p < 8; ++p) {
      float v0 = ts[cig * 16 + 2 * p][vl];
      float v1 = ts[cig * 16 + 2 * p + 1][vl];
      ushort h0 = bf16_bits(v0), h1 = bf16_bits(v1);
      float r0 = v0 - __bfloat162float(*reinterpret_cast<__hip_bfloat16*>(&h0));
      float r1 = v1 - __bfloat162float(*reinterpret_cast<__hip_bfloat16*>(&h1));
      h[p] = (uint)h0 | ((uint)h1 << 16);
      l[p] = (uint)bf16_bits(r0) | ((uint)bf16_bits(r1) << 16);
    }
    size_t base = (size_t)(vox0 + vl) * 64 + cig * 16;
    *reinterpret_cast<uint4*>(xh + base)     = make_uint4(h[0], h[1], h[2], h[3]);
    *reinterpret_cast<uint4*>(xh + base + 8) = make_uint4(h[4], h[5], h[6], h[7]);
    *reinterpret_cast<uint4*>(xl + base)     = make_uint4(l[0], l[1], l[2], l[3]);
    *reinterpret_cast<uint4*>(xl + base + 8) = make_uint4(l[4], l[5], l[6], l[7]);
    return;
  }
  const int bid = blockIdx.x - 512;
  if (bid < 128) {
    int tid = bid * 256 + t;
    int oc = tid & 511, g = (tid >> 9) & 3, khalf = (tid >> 11) & 1, tap = tid >> 12;
    uint h[4], l[4];
#pragma unroll
    for (int p = 0; p < 4; ++p) {
      int ci0 = khalf * 32 + g * 8 + 2 * p;
      float v0 = vw[oc * 512 + ci0 * 8 + tap];
      float v1 = vw[oc * 512 + (ci0 + 1) * 8 + tap];
      ushort h0 = bf16_bits(v0), h1 = bf16_bits(v1);
      float r0 = v0 - __bfloat162float(*reinterpret_cast<__hip_bfloat16*>(&h0));
      float r1 = v1 - __bfloat162float(*reinterpret_cast<__hip_bfloat16*>(&h1));
      h[p] = (uint)h0 | ((uint)h1 << 16);
      l[p] = (uint)bf16_bits(r0) | ((uint)bf16_bits(r1) << 16);
    }
    size_t base = (size_t)tid * 8;
    *reinterpret_cast<uint4*>(wfh + base) = make_uint4(h[0], h[1], h[2], h[3]);
    *reinterpret_cast<uint4*>(wfl + base) = make_uint4(l[0], l[1], l[2], l[3]);
  } else if (bid < 136) {
    int tid = (bid - 128) * 256 + t;
    if (tid < 32) bqk[tid] = tid < 16 ? q1b[tid] : k1b[tid - 16];
    int oc = tid & 31, g = (tid >> 5) & 3, khalf = (tid >> 7) & 1, tap = tid >> 8;
    const float* src = oc < 16 ? q1w + oc * 512 : k1w + (oc - 16) * 512;
    uint h[4], l[4];
#pragma unroll
    for (int p = 0; p < 4; ++p) {
      int ci0 = khalf * 32 + g * 8 + 2 * p;
      float v0 = src[ci0 * 8 + tap];
      float v1 = src[(ci0 + 1) * 8 + tap];
      ushort h0 = bf16_bits(v0), h1 = bf16_bits(v1);
      float r0 = v0 - __bfloat162float(*reinterpret_cast<__hip_bfloat16*>(&h0));
      float r1 = v1 - __bfloat162float(*reinterpret_cast<__hip_bfloat16*>(&h1));
      h[p] = (uint)h0 | ((uint)h1 << 16);
      l[p] = (uint)bf16_bits(r0) | ((uint)bf16_bits(r1) << 16);
    }
    size_t base = (size_t)tid * 8;
    *reinterpret_cast<uint4*>(wqh + base) = make_uint4(h[0], h[1], h[2], h[3]);
    *reinterpret_cast<uint4*>(wql + base) = make_uint4(l[0], l[1], l[2], l[3]);
  } else {
    int tid = (bid - 136) * 256 + t;
    if (tid < 96) b96[tid] = tid < 64 ? q2b[tid] : (tid < 72 ? k2b[tid - 64] : 0.f);
    int oc = tid % 96, g = (tid / 96) & 3, kslot = tid / 384;
    int khalf = kslot & 1, tap = kslot >> 1;
    uint h[4], l[4];
#pragma unroll
    for (int p = 0; p < 4; ++p) {
      float v[2];
#pragma unroll
      for (int q = 0; q < 2; ++q) {
        int ci = khalf * 32 + g * 8 + 2 * p + q;
        float w = 0.f;
        if (ci < 16) { if (oc < 64) w = q2w[(oc * 16 + ci) * 8 + tap]; }
        else if (ci < 32) {
          if (oc >= 64 && oc < 72) w = k2w[((oc - 64) * 16 + (ci - 16)) * 8 + tap];
        }
        v[q] = w;
      }
      ushort h0 = bf16_bits(v[0]), h1 = bf16_bits(v[1]);
      float r0 = v[0] - __bfloat162float(*reinterpret_cast<__hip_bfloat16*>(&h0));
      float r1 = v[1] - __bfloat162float(*reinterpret_cast<__hip_bfloat16*>(&h1));
      h[p] = (uint)h0 | ((uint)h1 << 16);
      l[p] = (uint)bf16_bits(r0) | ((uint)bf16_bits(r1) << 16);
    }
    size_t base = (size_t)tid * 8;
    *reinterpret_cast<uint4*>(w2h + base) = make_uint4(h[0], h[1], h[2], h[3]);
    *reinterpret_cast<uint4*>(w2l + base) = make_uint4(l[0], l[1], l[2], l[3]);
  }
}

// ---------------------------------------------------------------------------
// Normalize q1/k1 -> [vox][64] bf16 hi/lo, ci 32..63 zeroed (unchanged).
// ---------------------------------------------------------------------------
__global__ __launch_bounds__(256) void xprep2_kernel(
    const float* __restrict__ qk1, const float* __restrict__ np,
    ushort* __restrict__ xh, ushort* __restrict__ xl)
{
  __shared__ float ts[32][65];
  const int t = threadIdx.x;
  const int vox0 = blockIdx.x * 64;
#pragma unroll
  for (int i = 0; i < 8; ++i) {
    int e = i * 256 + t;
    int ci = e >> 6, vl = e & 63;
    float m = np[2 * ci], rs = np[2 * ci + 1];
    float v = qk1[(size_t)ci * VOX + vox0 + vl];
    ts[ci][vl] = fmaxf((v - m) * rs, 0.f);
  }
  __syncthreads();
  const int vl = t >> 2, cig = t & 3;
  uint h[8], l[8];
#pragma unroll
  for (int p = 0; p < 8; ++p) {
    if (cig < 2) {
      float v0 = ts[cig * 16 + 2 * p][vl];
      float v1 = ts[cig * 16 + 2 * p + 1][vl];
      ushort h0 = bf16_bits(v0), h1 = bf16_bits(v1);
      float r0 = v0 - __bfloat162float(*reinterpret_cast<__hip_bfloat16*>(&h0));
      float r1 = v1 - __bfloat162float(*reinterpret_cast<__hip_bfloat16*>(&h1));
      h[p] = (uint)h0 | ((uint)h1 << 16);
      l[p] = (uint)bf16_bits(r0) | ((uint)bf16_bits(r1) << 16);
    } else { h[p] = 0u; l[p] = 0u; }
  }
  size_t base = (size_t)(vox0 + vl) * 64 + cig * 16;
  *reinterpret_cast<uint4*>(xh + base)     = make_uint4(h[0], h[1], h[2], h[3]);
  *reinterpret_cast<uint4*>(xh + base + 8) = make_uint4(h[4], h[5], h[6], h[7]);
  *reinterpret_cast<uint4*>(xl + base)     = make_uint4(l[0], l[1], l[2], l[3]);
  *reinterpret_cast<uint4*>(xl + base + 8) = make_uint4(l[4], l[5], l[6], l[7]);
}

// ---------------------------------------------------------------------------
// MFMA conv body. Staging via global_load_lds (linear LDS dest, inverse-
// swizzled global source). Read side unchanged (swizzled).
// ---------------------------------------------------------------------------
template <int NMF, int OCS>
__device__ __forceinline__ void conv_mfma_body(
    ushort* Bs,
    const ushort* __restrict__ xh, const ushort* __restrict__ xl,
    const ushort* __restrict__ wh, const ushort* __restrict__ wl,
    const float* __restrict__ bias, float* __restrict__ y,
    float* __restrict__ part, const ushort* __restrict__ zpad,
    int bx, int nt, int t)
{
  const int wave = t >> 6, lane = t & 63;
  const int wm = wave >> 1, wn = wave & 1;
  const int g = lane >> 4, ww = lane & 15;
  const int m0 = bx * (NMF * 32);
  const int td = nt >> 4, th = (nt >> 1) & 7, tw = nt & 1;
  const int d0 = td * 2, h0 = th * 4, w0 = tw * 16;

  char* BsB = reinterpret_cast<char*>(Bs);
#pragma unroll
  for (int i = 0; i < 16; ++i) {
    const int s = i * 256 + t;                       // chunk 0..4095
    const int split = (s >= 2040 && s < 4080) ? 1 : 0;
    const int s2 = s - split * 2040;
    const bool tail = s >= 4080;
    const int pos = s2 >> 3;
    const int cig = (s2 & 7) ^ (pos & 7);
    const int dz = pos / 85, rem = pos - dz * 85;
    const int hz = rem / 17, wz = rem - hz * 17;
    const int d = d0 + dz, h = h0 + hz, w = w0 + wz;
    const bool ok = !tail && d < 32 && h < 32 && w < 32;
    const ushort* src = split ? xl : xh;
    const ushort* gp =
        ok ? (src + (size_t)(d * 1024 + h * 32 + w) * 64 + cig * 8) : zpad;
    __builtin_amdgcn_global_load_lds(
        (const __attribute__((address_space(1))) void*)gp,
        (__attribute__((address_space(3))) void*)(BsB + s * 16), 16, 0, 0);
  }
  __syncthreads();

  const int ocl = m0 + wm * (NMF * 16) + ww;
  f32x4 acc[NMF][4];
#pragma unroll
  for (int mf = 0; mf < NMF; ++mf)
#pragma unroll
    for (int hh = 0; hh < 4; ++hh) acc[mf][hh] = (f32x4){0.f, 0.f, 0.f, 0.f};

  for (int tap = 0; tap < 8; ++tap) {
    const int kd = tap >> 2, kh = (tap >> 1) & 1, kw = tap & 1;
#pragma unroll
    for (int khalf = 0; khalf < 2; ++khalf) {
      const size_t abase = ((size_t)((tap * 2 + khalf) * 4 + g) * OCS + ocl) * 8;
      s16x8 Ah[NMF], Al[NMF];
#pragma unroll
      for (int mf = 0; mf < NMF; ++mf) {
        Ah[mf] = *reinterpret_cast<const s16x8*>(wh + abase + mf * 16 * 8);
        Al[mf] = *reinterpret_cast<const s16x8*>(wl + abase + mf * 16 * 8);
      }
      const int srow = ((wn + kd) * 5 + kh) * 17 + kw;
#pragma unroll
      for (int hh = 0; hh < 4; ++hh) {
        int pos = srow + hh * 17 + ww;
        int baddr = (pos << 7) + khalf * 64 + g * 16;
        baddr ^= (pos & 7) << 4;
        const char* bp = reinterpret_cast<const char*>(Bs) + baddr;
        s16x8 Bh = *reinterpret_cast<const s16x8*>(bp);
        s16x8 Bl = *reinterpret_cast<const s16x8*>(bp + 32640);
#pragma unroll
        for (int mf = 0; mf < NMF; ++mf) {
          acc[mf][hh] = __builtin_amdgcn_mfma_f32_16x16x32_bf16(
              Ah[mf], Bh, acc[mf][hh], 0, 0, 0);
          acc[mf][hh] = __builtin_amdgcn_mfma_f32_16x16x32_bf16(
              Al[mf], Bh, acc[mf][hh], 0, 0, 0);
          acc[mf][hh] = __builtin_amdgcn_mfma_f32_16x16x32_bf16(
              Ah[mf], Bl, acc[mf][hh], 0, 0, 0);
        }
      }
    }
  }

  float bs[NMF][4];
#pragma unroll
  for (int mf = 0; mf < NMF; ++mf)
#pragma unroll
    for (int reg = 0; reg < 4; ++reg)
      bs[mf][reg] = bias[m0 + wm * (NMF * 16) + mf * 16 + g * 4 + reg];

  float ssum[NMF][4], ssq[NMF][4];
#pragma unroll
  for (int mf = 0; mf < NMF; ++mf)
#pragma unroll
    for (int reg = 0; reg < 4; ++reg) { ssum[mf][reg] = 0.f; ssq[mf][reg] = 0.f; }

#pragma unroll
  for (int mf = 0; mf < NMF; ++mf) {
#pragma unroll
    for (int hh = 0; hh < 4; ++hh) {
      int vox = (d0 + wn) * 1024 + (h0 + hh) * 32 + w0 + ww;
#pragma unroll
      for (int reg = 0; reg < 4; ++reg) {
        float v = acc[mf][hh][reg] + bs[mf][reg];
        int oc = m0 + wm * (NMF * 16) + mf * 16 + g * 4 + reg;
        y[(size_t)oc * VOX + vox] = v;
        ssum[mf][reg] += v;
        ssq[mf][reg] += v * v;
      }
    }
  }
#pragma unroll
  for (int mf = 0; mf < NMF; ++mf)
#pragma unroll
    for (int reg = 0; reg < 4; ++reg)
#pragma unroll
      for (int off = 1; off < 16; off <<= 1) {
        ssum[mf][reg] += __shfl_xor(ssum[mf][reg], off);
        ssq[mf][reg]  += __shfl_xor(ssq[mf][reg], off);
      }
  if ((lane & 15) == 0) {
    float* pp = part + (size_t)(nt * 2 + wn) * (OCS * 2);
#pragma unroll
    for (int mf = 0; mf < NMF; ++mf)
#pragma unroll
      for (int reg = 0; reg < 4; ++reg) {
        int oc = m0 + wm * (NMF * 16) + mf * 16 + g * 4 + reg;
        pp[oc * 2]     = ssum[mf][reg];
        pp[oc * 2 + 1] = ssq[mf][reg];
      }
  }
}

__global__ __launch_bounds__(256) void conv_fused_kernel(
    const ushort* __restrict__ xh, const ushort* __restrict__ xl,
    const ushort* __restrict__ wfh, const ushort* __restrict__ wfl,
    const float* __restrict__ vb, float* __restrict__ vraw,
    float* __restrict__ part_v,
    const ushort* __restrict__ wqh, const ushort* __restrict__ wql,
    const float* __restrict__ bqk, float* __restrict__ qk1,
    float* __restrict__ part_qk, const ushort* __restrict__ zpad)
{
  __shared__ ushort Bs[2 * 256 * 64];   // 64 KiB (last 256B = dead pad)
  const int bx = blockIdx.x, nt = blockIdx.y, t = threadIdx.x;
  if (bx < 2)
    conv_mfma_body<8, 512>(Bs, xh, xl, wfh, wfl, vb, vraw, part_v, zpad,
                           bx, nt, t);
  else
    conv_mfma_body<1, 32>(Bs, xh, xl, wqh, wql, bqk, qk1, part_qk, zpad,
                          0, nt, t);
}

template <int NMF, int OCS>
__global__ __launch_bounds__(256) void conv_v_mfma(
    const ushort* __restrict__ xh, const ushort* __restrict__ xl,
    const ushort* __restrict__ wh, const ushort* __restrict__ wl,
    const float* __restrict__ bias, float* __restrict__ y,
    float* __restrict__ part, const ushort* __restrict__ zpad)
{
  __shared__ ushort Bs[2 * 256 * 64];
  conv_mfma_body<NMF, OCS>(Bs, xh, xl, wh, wl, bias, y, part, zpad,
                           blockIdx.x, blockIdx.y, threadIdx.x);
}

// ---------------------------------------------------------------------------
// finalize3 v3: 16 channels/block x 16 workers/channel, shfl reduce.
// ---------------------------------------------------------------------------
__global__ __launch_bounds__(256) void finalize3_kernel(
    const float* __restrict__ p1, int C1, int NT1, float* __restrict__ n1,
    const float* __restrict__ p2, int C2, int NT2, float* __restrict__ n2,
    const float* __restrict__ p3, int C3, int NT3, float* __restrict__ n3)
{
  const int t = threadIdx.x;
  const int chl = t >> 4, w = t & 15;
  const int g = blockIdx.x * 16 + chl;

  const float* part = nullptr; float* np = nullptr; int C = 0, NT = 0, c = 0;
  if (g < C1)                { part = p1; np = n1; C = C1; NT = NT1; c = g; }
  else if (g < C1 + C2)      { part = p2; np = n2; C = C2; NT = NT2; c = g - C1; }
  else if (g < C1 + C2 + C3) { part = p3; np = n3; C = C3; NT = NT3; c = g - C1 - C2; }

  float s = 0.f, ss = 0.f;
  if (part)
    for (int tile = w; tile < NT; tile += 16) {
      float2 v = *reinterpret_cast<const float2*>(&part[((size_t)tile * C + c) * 2]);
      s += v.x; ss += v.y;
    }
#pragma unroll
  for (int off = 1; off < 16; off <<= 1) {
    s  += __shfl_xor(s, off);
    ss += __shfl_xor(ss, off);
  }
  if (w == 0 && part) {
    float m = s * INV_VOX;
    float var = ss * INV_VOX - m * m;
    np[2 * c]     = m;
    np[2 * c + 1] = rsqrtf(var + EPSF);
  }
}

// ---------------------------------------------------------------------------
// qk_box v2 (unchanged).
// ---------------------------------------------------------------------------
__global__ __launch_bounds__(256) void qk_box_kernel(
    const float* __restrict__ qraw, const float* __restrict__ npq,
    const float* __restrict__ kraw, const float* __restrict__ npk,
    float* __restrict__ qkout)
{
  __shared__ float s[1000];
  __shared__ float ws2[800];
  const int j = blockIdx.y;
  const int tile = blockIdx.x;
  const int W0 = (tile & 7) * 8, H0 = ((tile >> 3) & 7) * 8, D0 = (tile >> 6) * 8;
  const int t = threadIdx.x;
  const int cbD = (D0 >> 1) - 1, cbH = (H0 >> 1) - 1, cbW = (W0 >> 1) - 1;
  const float2* npq2 = reinterpret_cast<const float2*>(npq);
  const float2* npk2 = reinterpret_cast<const float2*>(npk);

#pragma unroll
  for (int kk = 0; kk < 7; ++kk) {
    int f = t + kk * 256;
    if (f < 1728) {
      int par = f / 216, idx = f - par * 216;
      int dz = idx / 36, r2 = idx - dz * 36, hz = r2 / 6, wz = r2 - hz * 6;
      int pd = (par >> 2) & 1, ph = (par >> 1) & 1, pw = par & 1;
      int dzf = 2 * dz + pd - 1, hzf = 2 * hz + ph - 1, wzf = 2 * wz + pw - 1;
      if ((unsigned)dzf < 10u && (unsigned)hzf < 10u && (unsigned)wzf < 10u) {
        int cD = cbD + dz, cH = cbH + hz, cW = cbW + wz;
        float prod = 0.f;
        if ((unsigned)cD < 32u && (unsigned)cH < 32u && (unsigned)cW < 32u) {
          int cidx = cD * 1024 + cH * 32 + cW;
          int qc = j * 8 + par;
          float2 nq = npq2[qc];
          float2 nk = npk2[par];
          float qv = fmaxf((qraw[(size_t)qc * VOX + cidx] - nq.x) * nq.y, 0.f);
          float kv = fmaxf((kraw[(size_t)par * VOX + cidx] - nk.x) * nk.y, 0.f);
          prod = qv * kv;
        }
        s[dzf * 100 + hzf * 10 + wzf] = prod;
      }
    }
  }
  __syncthreads();
#pragma unroll
  for (int i = 0; i < 4; ++i) {
    int e = t + i * 256;
    if (e < 800) {
      int dz = e / 80, r2 = e - dz * 80, hz = r2 >> 3, wz1 = r2 & 7;
      int base = dz * 100 + hz * 10 + wz1;
      ws2[e] = s[base] + s[base + 1] + s[base + 2];
    }
  }
  __syncthreads();
#pragma unroll
  for (int rep = 0; rep < 2; ++rep) {
    int o = t + rep * 256;
    int wz = o & 7, hz = (o >> 3) & 7, dz = o >> 6;
    int wb = dz * 80 + hz * 8 + wz;
    float sum = 0.f;
#pragma unroll
    for (int a = 0; a < 3; ++a)
      sum += ws2[wb + a * 80] + ws2[wb + a * 80 + 8] + ws2[wb + a * 80 + 16];
    qkout[(size_t)j * 262144 + (D0 + dz) * 4096 + (H0 + hz) * 64 + (W0 + wz)] =
        sum * (1.f / 27.f);
  }
}

// ---------------------------------------------------------------------------
// einsum_box v10 + XCD swizzle: flat grid 2048; bijective remap keeps all
// 4 sibling blocks of a tile on one XCD (ids congruent mod 8).
// ---------------------------------------------------------------------------
__global__ __launch_bounds__(256) void einsum_box_kernel(
    const float* __restrict__ vraw, const float* __restrict__ npv,
    const float* __restrict__ qk, float* __restrict__ out)
{
  __shared__ char vs_raw[2][6912];
  __shared__ float qkvs[1000];
  __shared__ float wsum[800];

  // XCD-locality remap: bid -> (tile, sub). blocks with equal (bid&7) land
  // on the same XCD (dispatch round-robin); give each XCD 64 whole tiles.
  const int bid = blockIdx.x;           // 0..2047
  const int xcd = bid & 7;
  const int k9 = bid >> 3;              // 0..255
  const int tile = xcd * 64 + (k9 >> 2);
  const int sub = k9 & 3;
  const int c0 = (sub & 1) * 32;
  const int ciBase = ((sub >> 1) & 1) * 16;

  const int W0 = (tile & 7) * 8, H0 = ((tile >> 3) & 7) * 8, D0 = (tile >> 6) * 8;
  const int t = threadIdx.x;
  const int cbD = (D0 >> 1) - 1, cbH = (H0 >> 1) - 1, cbW = (W0 >> 1) - 1;
  const float2* npv2 = reinterpret_cast<const float2*>(npv);

  uint soff[7]; int sbyte[7]; int snidx[7]; bool svalid[7];
#pragma unroll
  for (int k = 0; k < 7; ++k) {
    int f = t + k * 256;
    int j = f / 216, idx = f - j * 216;
    int dz = idx / 36, r2 = idx - dz * 36, hz = r2 / 6, wz = r2 - hz * 6;
    int cD = cbD + dz, cH = cbH + hz, cW = cbW + wz;
    bool vld = (f < 1728) && (unsigned)cD < 32u && (unsigned)cH < 32u &&
               (unsigned)cW < 32u;
    svalid[k] = vld;
    soff[k] = vld ? (uint)((c0 * 8 + j) * VOX + cD * 1024 + cH * 32 + cW) : 0u;
    snidx[k] = (f < 1728) ? (c0 * 8 + j) : 0;
    int byte = idx * 32 + (j >> 2) * 16 + (j & 3) * 4;
    sbyte[k] = byte ^ (((idx >> 2) & 7) << 4);
  }

  int vbyte[4]; float qr[4][8];
#pragma unroll
  for (int i = 0; i < 4; ++i) {
    int pos = t + i * 256;
    vbyte[i] = 0;
#pragma unroll
    for (int j = 0; j < 8; ++j) qr[i][j] = 0.f;
    if (pos < 1000) {
      int dz = pos / 100, rem = pos - dz * 100, hz = rem / 10, wz = rem - hz * 10;
      int D = D0 - 1 + dz, H = H0 - 1 + hz, W = W0 - 1 + wz;
      if ((unsigned)D < 64u && (unsigned)H < 64u && (unsigned)W < 64u) {
        int fidx = D * 4096 + H * 64 + W;
#pragma unroll
        for (int j = 0; j < 8; ++j)
          qr[i][j] = qk[(size_t)j * 262144 + fidx];
        int vidx = ((D >> 1) - cbD) * 36 + ((H >> 1) - cbH) * 6 + ((W >> 1) - cbW);
        vbyte[i] = (vidx * 32) ^ (((vidx >> 2) & 7) << 4);
      }
    }
  }

  int wb[4];
#pragma unroll
  for (int i = 0; i < 4; ++i) {
    int e = t + i * 256;
    int dz = e / 80, r2 = e - dz * 80, hz = r2 >> 3, wz1 = r2 & 7;
    wb[i] = dz * 100 + hz * 10 + wz1;
  }
  int wb2[2]; float* op[2];
#pragma unroll
  for (int rep = 0; rep < 2; ++rep) {
    int o = t + rep * 256;
    int wz = o & 7, hz = (o >> 3) & 7, dz = o >> 6;
    wb2[rep] = dz * 80 + hz * 8 + wz;
    op[rep] = out + (size_t)c0 * 262144 +
              (D0 + dz) * 4096 + (H0 + hz) * 64 + (W0 + wz);
  }

  float pre[7];
  auto fetchv = [&](int ci) {
    const uint cio = (uint)(ci * 8 * VOX);
    const int cin8 = ci * 8;
#pragma unroll
    for (int k = 0; k < 7; ++k) {
      if (k < 6 || t < 192) {
        float2 mr = npv2[snidx[k] + cin8];
        float raw = vraw[soff[k] + cio];
        pre[k] = svalid[k] ? fmaxf((raw - mr.x) * mr.y, 0.f) : 0.f;
      }
    }
  };

  fetchv(ciBase);
#pragma unroll
  for (int k = 0; k < 7; ++k)
    if (k < 6 || t < 192)
      *reinterpret_cast<float*>(vs_raw[0] + sbyte[k]) = pre[k];
  fetchv(ciBase + 1);
  __syncthreads();

  for (int li = 0; li < 16; ++li) {
    const int ci = ciBase + li;
    const int cbuf = li & 1;
    if (li < 15) {
#pragma unroll
      for (int k = 0; k < 7; ++k)
        if (k < 6 || t < 192)
          *reinterpret_cast<float*>(vs_raw[cbuf ^ 1] + sbyte[k]) = pre[k];
      if (li < 14) fetchv(ci + 2);
    }
#pragma unroll
    for (int i = 0; i < 4; ++i) {
      int pos = t + i * 256;
      if (pos < 1000) {
        const char* vb0 = vs_raw[cbuf];
        float4 va = *reinterpret_cast<const float4*>(vb0 + vbyte[i]);
        float4 vb = *reinterpret_cast<const float4*>(vb0 + (vbyte[i] ^ 16));
        float val = qr[i][0] * va.x;
        val = fmaf(qr[i][1], va.y, val);
        val = fmaf(qr[i][2], va.z, val);
        val = fmaf(qr[i][3], va.w, val);
        val = fmaf(qr[i][4], vb.x, val);
        val = fmaf(qr[i][5], vb.y, val);
        val = fmaf(qr[i][6], vb.z, val);
        val = fmaf(qr[i][7], vb.w, val);
        qkvs[pos] = val;
      }
    }
    __syncthreads();
#pragma unroll
    for (int i = 0; i < 4; ++i) {
      if (i < 3 || t < 32) {
        int b = wb[i];
        wsum[t + i * 256] = qkvs[b] + qkvs[b + 1] + qkvs[b + 2];
      }
    }
    __syncthreads();
#pragma unroll
    for (int rep = 0; rep < 2; ++rep) {
      float sum = 0.f;
#pragma unroll
      for (int a = 0; a < 3; ++a)
        sum += wsum[wb2[rep] + a * 80] + wsum[wb2[rep] + a * 80 + 8] +
               wsum[wb2[rep] + a * 80 + 16];
      op[rep][(size_t)ci << 18] = sum * (1.f / 27.f);
    }
  }
}

// ---------------------------------------------------------------------------
extern "C" void kernel_launch(void* const* d_in, const int* in_sizes, int n_in,
                              void* d_out, int out_size, void* d_ws, size_t ws_size,
                              hipStream_t stream)
{
  (void)in_sizes; (void)n_in; (void)out_size; (void)ws_size;
  const float* x   = (const float*)d_in[0];
  const float* q1w = (const float*)d_in[1];
  const float* q1b = (const float*)d_in[2];
  const float* q2w = (const float*)d_in[3];
  const float* q2b = (const float*)d_in[4];
  const float* k1w = (const float*)d_in[5];
  const float* k1b = (const float*)d_in[6];
  const float* k2w = (const float*)d_in[7];
  const float* k2b = (const float*)d_in[8];
  const float* vw  = (const float*)d_in[9];
  const float* vb  = (const float*)d_in[10];
  float* out = (float*)d_out;

  float* p = (float*)d_ws;
  float* vraw    = p; p += (size_t)512 * VOX;      // 64 MiB
  float* regionR = p; p += (size_t)96 * VOX;       // 12 MiB: qk1raw then y96
  float* qkbuf   = p; p += (size_t)8 * 262144;     // 8 MiB: xT / xT2 / qk
  float* part_v  = p; p += (size_t)512 * 512 * 2;
  float* part_qk = p; p += (size_t)512 * 32 * 2;
  float* part96  = p; p += (size_t)512 * 96 * 2;
  float* WfF     = p; p += (size_t)262144;
  float* WqF     = p; p += (size_t)16384;
  float* W2F     = p; p += (size_t)49152;
  float* np_qk1  = p; p += 64;
  float* np96    = p; p += 192;
  float* np_v    = p; p += 1024;
  float* bqk     = p; p += 32;
  float* b96     = p; p += 96;
  float* zpadf   = p; p += 4;                      // 16B zero guard

  float* qk1raw = regionR;
  float* y96    = regionR;

  ushort* xT_hi = (ushort*)qkbuf;
  ushort* xT_lo = (ushort*)qkbuf + (size_t)32768 * 64;
  ushort* Wf_hi = (ushort*)WfF;
  ushort* Wf_lo = (ushort*)WfF + 262144;
  ushort* Wq_hi = (ushort*)WqF;
  ushort* Wq_lo = (ushort*)WqF + 16384;
  ushort* W2_hi = (ushort*)W2F;
  ushort* W2_lo = (ushort*)W2F + 49152;
  const ushort* zpad = (const ushort*)zpadf;

  dim3 blk(256);
  prep_all_kernel<<<672, blk, 0, stream>>>(
      x, vw, q1w, q1b, k1w, k1b, q2w, q2b, k2w, k2b,
      xT_hi, xT_lo, Wf_hi, Wf_lo, Wq_hi, Wq_lo, bqk, W2_hi, W2_lo, b96, zpadf);
  conv_fused_kernel<<<dim3(3, 256), blk, 0, stream>>>(
      xT_hi, xT_lo, Wf_hi, Wf_lo, vb, vraw, part_v,
      Wq_hi, Wq_lo, bqk, qk1raw, part_qk, zpad);
  finalize3_kernel<<<34, blk, 0, stream>>>(
      part_v, 512, 512, np_v,
      part_qk, 32, 512, np_qk1,
      nullptr, 0, 0, nullptr);
  xprep2_kernel<<<512, blk, 0, stream>>>(qk1raw, np_qk1, xT_hi, xT_lo);
  conv_v_mfma<3, 96><<<dim3(1, 256), blk, 0, stream>>>(
      xT_hi, xT_lo, W2_hi, W2_lo, b96, y96, part96, zpad);
  finalize3_kernel<<<6, blk, 0, stream>>>(
      part96, 96, 512, np96,
      nullptr, 0, 0, nullptr,
      nullptr, 0, 0, nullptr);
  qk_box_kernel<<<dim3(512, 8), blk, 0, stream>>>(
      y96, np96, y96 + (size_t)64 * VOX, np96 + 128, qkbuf);
  einsum_box_kernel<<<2048, blk, 0, stream>>>(
      vraw, np_v, qkbuf, out);
}

// Round 22
// 263.746 us; speedup vs baseline: 1.4239x; 1.0062x over previous
//
#include <hip/hip_runtime.h>
#include <hip/hip_bf16.h>

// QKV upsampling pipeline.
// R22: T1 XCD-grouping extended to conv_fused (flat 768: 3 oc-siblings of a
// spatial tile share one XCD's L2 -> xT halo fetched once, not 3x) and
// qk_box (flat 4096: 8 j-siblings + 64 contiguous tiles per XCD).
// einsum = R21 (XCD-swizzled v10, 120.7us). Rest identical to R21 (265.4us).

constexpr int VOX = 32 * 32 * 32;
constexpr float INV_VOX = 1.0f / 32768.0f;
constexpr float EPSF = 1e-5f;

typedef __attribute__((ext_vector_type(8))) short s16x8;
typedef __attribute__((ext_vector_type(4))) float f32x4;

static __device__ __forceinline__ ushort bf16_bits(float v) {
  __hip_bfloat16 h = __float2bfloat16(v);
  return *reinterpret_cast<ushort*>(&h);
}

// ---------------------------------------------------------------------------
// Merged x-transpose (blocks 0-511) + weight prepack (blocks 512-671).
// Block 0 also zeroes the 16B zpad guard.
// ---------------------------------------------------------------------------
__global__ __launch_bounds__(256) void prep_all_kernel(
    const float* __restrict__ x,
    const float* __restrict__ vw,
    const float* __restrict__ q1w, const float* __restrict__ q1b,
    const float* __restrict__ k1w, const float* __restrict__ k1b,
    const float* __restrict__ q2w, const float* __restrict__ q2b,
    const float* __restrict__ k2w, const float* __restrict__ k2b,
    ushort* __restrict__ xh, ushort* __restrict__ xl,
    ushort* __restrict__ wfh, ushort* __restrict__ wfl,
    ushort* __restrict__ wqh, ushort* __restrict__ wql, float* __restrict__ bqk,
    ushort* __restrict__ w2h, ushort* __restrict__ w2l, float* __restrict__ b96,
    float* __restrict__ zpad)
{
  __shared__ float ts[64][65];
  const int t = threadIdx.x;
  if ((int)blockIdx.x < 512) {
    if (blockIdx.x == 0 && t == 0)
      *reinterpret_cast<uint4*>(zpad) = make_uint4(0u, 0u, 0u, 0u);
    const int vox0 = blockIdx.x * 64;
#pragma unroll
    for (int i = 0; i < 16; ++i) {
      int e = i * 256 + t;
      int ci = e >> 6, vl = e & 63;
      ts[ci][vl] = x[(size_t)ci * VOX + vox0 + vl];
    }
    __syncthreads();
    const int vl = t >> 2, cig = t & 3;
    uint h[8], l[8];
#pragma unroll
    for (int p = 0; p < 8; ++p) {
      float v0 = ts[cig * 16 + 2 * p][vl];
      float v1 = ts[cig * 16 + 2 * p + 1][vl];
      ushort h0 = bf16_bits(v0), h1 = bf16_bits(v1);
      float r0 = v0 - __bfloat162float(*reinterpret_cast<__hip_bfloat16*>(&h0));
      float r1 = v1 - __bfloat162float(*reinterpret_cast<__hip_bfloat16*>(&h1));
      h[p] = (uint)h0 | ((uint)h1 << 16);
      l[p] = (uint)bf16_bits(r0) | ((uint)bf16_bits(r1) << 16);
    }
    size_t base = (size_t)(vox0 + vl) * 64 + cig * 16;
    *reinterpret_cast<uint4*>(xh + base)     = make_uint4(h[0], h[1], h[2], h[3]);
    *reinterpret_cast<uint4*>(xh + base + 8) = make_uint4(h[4], h[5], h[6], h[7]);
    *reinterpret_cast<uint4*>(xl + base)     = make_uint4(l[0], l[1], l[2], l[3]);
    *reinterpret_cast<uint4*>(xl + base + 8) = make_uint4(l[4], l[5], l[6], l[7]);
    return;
  }
  const int bid = blockIdx.x - 512;
  if (bid < 128) {
    int tid = bid * 256 + t;
    int oc = tid & 511, g = (tid >> 9) & 3, khalf = (tid >> 11) & 1, tap = tid >> 12;
    uint h[4], l[4];
#pragma unroll
    for (int p = 0; p < 4; ++p) {
      int ci0 = khalf * 32 + g * 8 + 2 * p;
      float v0 = vw[oc * 512 + ci0 * 8 + tap];
      float v1 = vw[oc * 512 + (ci0 + 1) * 8 + tap];
      ushort h0 = bf16_bits(v0), h1 = bf16_bits(v1);
      float r0 = v0 - __bfloat162float(*reinterpret_cast<__hip_bfloat16*>(&h0));
      float r1 = v1 - __bfloat162float(*reinterpret_cast<__hip_bfloat16*>(&h1));
      h[p] = (uint)h0 | ((uint)h1 << 16);
      l[p] = (uint)bf16_bits(r0) | ((uint)bf16_bits(r1) << 16);
    }
    size_t base = (size_t)tid * 8;
    *reinterpret_cast<uint4*>(wfh + base) = make_uint4(h[0], h[1], h[2], h[3]);
    *reinterpret_cast<uint4*>(wfl + base) = make_uint4(l[0], l[1], l[2], l[3]);
  } else if (bid < 136) {
    int tid = (bid - 128) * 256 + t;
    if (tid < 32) bqk[tid] = tid < 16 ? q1b[tid] : k1b[tid - 16];
    int oc = tid & 31, g = (tid >> 5) & 3, khalf = (tid >> 7) & 1, tap = tid >> 8;
    const float* src = oc < 16 ? q1w + oc * 512 : k1w + (oc - 16) * 512;
    uint h[4], l[4];
#pragma unroll
    for (int p = 0; p < 4; ++p) {
      int ci0 = khalf * 32 + g * 8 + 2 * p;
      float v0 = src[ci0 * 8 + tap];
      float v1 = src[(ci0 + 1) * 8 + tap];
      ushort h0 = bf16_bits(v0), h1 = bf16_bits(v1);
      float r0 = v0 - __bfloat162float(*reinterpret_cast<__hip_bfloat16*>(&h0));
      float r1 = v1 - __bfloat162float(*reinterpret_cast<__hip_bfloat16*>(&h1));
      h[p] = (uint)h0 | ((uint)h1 << 16);
      l[p] = (uint)bf16_bits(r0) | ((uint)bf16_bits(r1) << 16);
    }
    size_t base = (size_t)tid * 8;
    *reinterpret_cast<uint4*>(wqh + base) = make_uint4(h[0], h[1], h[2], h[3]);
    *reinterpret_cast<uint4*>(wql + base) = make_uint4(l[0], l[1], l[2], l[3]);
  } else {
    int tid = (bid - 136) * 256 + t;
    if (tid < 96) b96[tid] = tid < 64 ? q2b[tid] : (tid < 72 ? k2b[tid - 64] : 0.f);
    int oc = tid % 96, g = (tid / 96) & 3, kslot = tid / 384;
    int khalf = kslot & 1, tap = kslot >> 1;
    uint h[4], l[4];
#pragma unroll
    for (int p = 0; p < 4; ++p) {
      float v[2];
#pragma unroll
      for (int q = 0; q < 2; ++q) {
        int ci = khalf * 32 + g * 8 + 2 * p + q;
        float w = 0.f;
        if (ci < 16) { if (oc < 64) w = q2w[(oc * 16 + ci) * 8 + tap]; }
        else if (ci < 32) {
          if (oc >= 64 && oc < 72) w = k2w[((oc - 64) * 16 + (ci - 16)) * 8 + tap];
        }
        v[q] = w;
      }
      ushort h0 = bf16_bits(v[0]), h1 = bf16_bits(v[1]);
      float r0 = v[0] - __bfloat162float(*reinterpret_cast<__hip_bfloat16*>(&h0));
      float r1 = v[1] - __bfloat162float(*reinterpret_cast<__hip_bfloat16*>(&h1));
      h[p] = (uint)h0 | ((uint)h1 << 16);
      l[p] = (uint)bf16_bits(r0) | ((uint)bf16_bits(r1) << 16);
    }
    size_t base = (size_t)tid * 8;
    *reinterpret_cast<uint4*>(w2h + base) = make_uint4(h[0], h[1], h[2], h[3]);
    *reinterpret_cast<uint4*>(w2l + base) = make_uint4(l[0], l[1], l[2], l[3]);
  }
}

// ---------------------------------------------------------------------------
// Normalize q1/k1 -> [vox][64] bf16 hi/lo, ci 32..63 zeroed (unchanged).
// ---------------------------------------------------------------------------
__global__ __launch_bounds__(256) void xprep2_kernel(
    const float* __restrict__ qk1, const float* __restrict__ np,
    ushort* __restrict__ xh, ushort* __restrict__ xl)
{
  __shared__ float ts[32][65];
  const int t = threadIdx.x;
  const int vox0 = blockIdx.x * 64;
#pragma unroll
  for (int i = 0; i < 8; ++i) {
    int e = i * 256 + t;
    int ci = e >> 6, vl = e & 63;
    float m = np[2 * ci], rs = np[2 * ci + 1];
    float v = qk1[(size_t)ci * VOX + vox0 + vl];
    ts[ci][vl] = fmaxf((v - m) * rs, 0.f);
  }
  __syncthreads();
  const int vl = t >> 2, cig = t & 3;
  uint h[8], l[8];
#pragma unroll
  for (int p = 0; p < 8; ++p) {
    if (cig < 2) {
      float v0 = ts[cig * 16 + 2 * p][vl];
      float v1 = ts[cig * 16 + 2 * p + 1][vl];
      ushort h0 = bf16_bits(v0), h1 = bf16_bits(v1);
      float r0 = v0 - __bfloat162float(*reinterpret_cast<__hip_bfloat16*>(&h0));
      float r1 = v1 - __bfloat162float(*reinterpret_cast<__hip_bfloat16*>(&h1));
      h[p] = (uint)h0 | ((uint)h1 << 16);
      l[p] = (uint)bf16_bits(r0) | ((uint)bf16_bits(r1) << 16);
    } else { h[p] = 0u; l[p] = 0u; }
  }
  size_t base = (size_t)(vox0 + vl) * 64 + cig * 16;
  *reinterpret_cast<uint4*>(xh + base)     = make_uint4(h[0], h[1], h[2], h[3]);
  *reinterpret_cast<uint4*>(xh + base + 8) = make_uint4(h[4], h[5], h[6], h[7]);
  *reinterpret_cast<uint4*>(xl + base)     = make_uint4(l[0], l[1], l[2], l[3]);
  *reinterpret_cast<uint4*>(xl + base + 8) = make_uint4(l[4], l[5], l[6], l[7]);
}

// ---------------------------------------------------------------------------
// MFMA conv body. Staging via global_load_lds (linear LDS dest, inverse-
// swizzled global source). Read side unchanged (swizzled).
// ---------------------------------------------------------------------------
template <int NMF, int OCS>
__device__ __forceinline__ void conv_mfma_body(
    ushort* Bs,
    const ushort* __restrict__ xh, const ushort* __restrict__ xl,
    const ushort* __restrict__ wh, const ushort* __restrict__ wl,
    const float* __restrict__ bias, float* __restrict__ y,
    float* __restrict__ part, const ushort* __restrict__ zpad,
    int bx, int nt, int t)
{
  const int wave = t >> 6, lane = t & 63;
  const int wm = wave >> 1, wn = wave & 1;
  const int g = lane >> 4, ww = lane & 15;
  const int m0 = bx * (NMF * 32);
  const int td = nt >> 4, th = (nt >> 1) & 7, tw = nt & 1;
  const int d0 = td * 2, h0 = th * 4, w0 = tw * 16;

  char* BsB = reinterpret_cast<char*>(Bs);
#pragma unroll
  for (int i = 0; i < 16; ++i) {
    const int s = i * 256 + t;                       // chunk 0..4095
    const int split = (s >= 2040 && s < 4080) ? 1 : 0;
    const int s2 = s - split * 2040;
    const bool tail = s >= 4080;
    const int pos = s2 >> 3;
    const int cig = (s2 & 7) ^ (pos & 7);
    const int dz = pos / 85, rem = pos - dz * 85;
    const int hz = rem / 17, wz = rem - hz * 17;
    const int d = d0 + dz, h = h0 + hz, w = w0 + wz;
    const bool ok = !tail && d < 32 && h < 32 && w < 32;
    const ushort* src = split ? xl : xh;
    const ushort* gp =
        ok ? (src + (size_t)(d * 1024 + h * 32 + w) * 64 + cig * 8) : zpad;
    __builtin_amdgcn_global_load_lds(
        (const __attribute__((address_space(1))) void*)gp,
        (__attribute__((address_space(3))) void*)(BsB + s * 16), 16, 0, 0);
  }
  __syncthreads();

  const int ocl = m0 + wm * (NMF * 16) + ww;
  f32x4 acc[NMF][4];
#pragma unroll
  for (int mf = 0; mf < NMF; ++mf)
#pragma unroll
    for (int hh = 0; hh < 4; ++hh) acc[mf][hh] = (f32x4){0.f, 0.f, 0.f, 0.f};

  for (int tap = 0; tap < 8; ++tap) {
    const int kd = tap >> 2, kh = (tap >> 1) & 1, kw = tap & 1;
#pragma unroll
    for (int khalf = 0; khalf < 2; ++khalf) {
      const size_t abase = ((size_t)((tap * 2 + khalf) * 4 + g) * OCS + ocl) * 8;
      s16x8 Ah[NMF], Al[NMF];
#pragma unroll
      for (int mf = 0; mf < NMF; ++mf) {
        Ah[mf] = *reinterpret_cast<const s16x8*>(wh + abase + mf * 16 * 8);
        Al[mf] = *reinterpret_cast<const s16x8*>(wl + abase + mf * 16 * 8);
      }
      const int srow = ((wn + kd) * 5 + kh) * 17 + kw;
#pragma unroll
      for (int hh = 0; hh < 4; ++hh) {
        int pos = srow + hh * 17 + ww;
        int baddr = (pos << 7) + khalf * 64 + g * 16;
        baddr ^= (pos & 7) << 4;
        const char* bp = reinterpret_cast<const char*>(Bs) + baddr;
        s16x8 Bh = *reinterpret_cast<const s16x8*>(bp);
        s16x8 Bl = *reinterpret_cast<const s16x8*>(bp + 32640);
#pragma unroll
        for (int mf = 0; mf < NMF; ++mf) {
          acc[mf][hh] = __builtin_amdgcn_mfma_f32_16x16x32_bf16(
              Ah[mf], Bh, acc[mf][hh], 0, 0, 0);
          acc[mf][hh] = __builtin_amdgcn_mfma_f32_16x16x32_bf16(
              Al[mf], Bh, acc[mf][hh], 0, 0, 0);
          acc[mf][hh] = __builtin_amdgcn_mfma_f32_16x16x32_bf16(
              Ah[mf], Bl, acc[mf][hh], 0, 0, 0);
        }
      }
    }
  }

  float bs[NMF][4];
#pragma unroll
  for (int mf = 0; mf < NMF; ++mf)
#pragma unroll
    for (int reg = 0; reg < 4; ++reg)
      bs[mf][reg] = bias[m0 + wm * (NMF * 16) + mf * 16 + g * 4 + reg];

  float ssum[NMF][4], ssq[NMF][4];
#pragma unroll
  for (int mf = 0; mf < NMF; ++mf)
#pragma unroll
    for (int reg = 0; reg < 4; ++reg) { ssum[mf][reg] = 0.f; ssq[mf][reg] = 0.f; }

#pragma unroll
  for (int mf = 0; mf < NMF; ++mf) {
#pragma unroll
    for (int hh = 0; hh < 4; ++hh) {
      int vox = (d0 + wn) * 1024 + (h0 + hh) * 32 + w0 + ww;
#pragma unroll
      for (int reg = 0; reg < 4; ++reg) {
        float v = acc[mf][hh][reg] + bs[mf][reg];
        int oc = m0 + wm * (NMF * 16) + mf * 16 + g * 4 + reg;
        y[(size_t)oc * VOX + vox] = v;
        ssum[mf][reg] += v;
        ssq[mf][reg] += v * v;
      }
    }
  }
#pragma unroll
  for (int mf = 0; mf < NMF; ++mf)
#pragma unroll
    for (int reg = 0; reg < 4; ++reg)
#pragma unroll
      for (int off = 1; off < 16; off <<= 1) {
        ssum[mf][reg] += __shfl_xor(ssum[mf][reg], off);
        ssq[mf][reg]  += __shfl_xor(ssq[mf][reg], off);
      }
  if ((lane & 15) == 0) {
    float* pp = part + (size_t)(nt * 2 + wn) * (OCS * 2);
#pragma unroll
    for (int mf = 0; mf < NMF; ++mf)
#pragma unroll
      for (int reg = 0; reg < 4; ++reg) {
        int oc = m0 + wm * (NMF * 16) + mf * 16 + g * 4 + reg;
        pp[oc * 2]     = ssum[mf][reg];
        pp[oc * 2 + 1] = ssq[mf][reg];
      }
  }
}

// conv_fused with XCD grouping: flat grid 768 (= 8 XCD x 32 nt x 3 bx).
__global__ __launch_bounds__(256) void conv_fused_kernel(
    const ushort* __restrict__ xh, const ushort* __restrict__ xl,
    const ushort* __restrict__ wfh, const ushort* __restrict__ wfl,
    const float* __restrict__ vb, float* __restrict__ vraw,
    float* __restrict__ part_v,
    const ushort* __restrict__ wqh, const ushort* __restrict__ wql,
    const float* __restrict__ bqk, float* __restrict__ qk1,
    float* __restrict__ part_qk, const ushort* __restrict__ zpad)
{
  __shared__ ushort Bs[2 * 256 * 64];   // 64 KiB (last 256B = dead pad)
  const int bid = blockIdx.x;           // 0..767
  const int xcd = bid & 7;
  const int k = bid >> 3;               // 0..95
  const int nt = xcd * 32 + k / 3;      // 0..255 (bijective: 768%8==0)
  const int bx = k - (k / 3) * 3;       // 0..2
  const int t = threadIdx.x;
  if (bx < 2)
    conv_mfma_body<8, 512>(Bs, xh, xl, wfh, wfl, vb, vraw, part_v, zpad,
                           bx, nt, t);
  else
    conv_mfma_body<1, 32>(Bs, xh, xl, wqh, wql, bqk, qk1, part_qk, zpad,
                          0, nt, t);
}

template <int NMF, int OCS>
__global__ __launch_bounds__(256) void conv_v_mfma(
    const ushort* __restrict__ xh, const ushort* __restrict__ xl,
    const ushort* __restrict__ wh, const ushort* __restrict__ wl,
    const float* __restrict__ bias, float* __restrict__ y,
    float* __restrict__ part, const ushort* __restrict__ zpad)
{
  __shared__ ushort Bs[2 * 256 * 64];
  conv_mfma_body<NMF, OCS>(Bs, xh, xl, wh, wl, bias, y, part, zpad,
                           blockIdx.x, blockIdx.y, threadIdx.x);
}

// ---------------------------------------------------------------------------
// finalize3 v3: 16 channels/block x 16 workers/channel, shfl reduce.
// ---------------------------------------------------------------------------
__global__ __launch_bounds__(256) void finalize3_kernel(
    const float* __restrict__ p1, int C1, int NT1, float* __restrict__ n1,
    const float* __restrict__ p2, int C2, int NT2, float* __restrict__ n2,
    const float* __restrict__ p3, int C3, int NT3, float* __restrict__ n3)
{
  const int t = threadIdx.x;
  const int chl = t >> 4, w = t & 15;
  const int g = blockIdx.x * 16 + chl;

  const float* part = nullptr; float* np = nullptr; int C = 0, NT = 0, c = 0;
  if (g < C1)                { part = p1; np = n1; C = C1; NT = NT1; c = g; }
  else if (g < C1 + C2)      { part = p2; np = n2; C = C2; NT = NT2; c = g - C1; }
  else if (g < C1 + C2 + C3) { part = p3; np = n3; C = C3; NT = NT3; c = g - C1 - C2; }

  float s = 0.f, ss = 0.f;
  if (part)
    for (int tile = w; tile < NT; tile += 16) {
      float2 v = *reinterpret_cast<const float2*>(&part[((size_t)tile * C + c) * 2]);
      s += v.x; ss += v.y;
    }
#pragma unroll
  for (int off = 1; off < 16; off <<= 1) {
    s  += __shfl_xor(s, off);
    ss += __shfl_xor(ss, off);
  }
  if (w == 0 && part) {
    float m = s * INV_VOX;
    float var = ss * INV_VOX - m * m;
    np[2 * c]     = m;
    np[2 * c + 1] = rsqrtf(var + EPSF);
  }
}

// ---------------------------------------------------------------------------
// qk_box v2 + XCD grouping: flat grid 4096 (= 8 XCD x 64 tiles x 8 j).
// ---------------------------------------------------------------------------
__global__ __launch_bounds__(256) void qk_box_kernel(
    const float* __restrict__ qraw, const float* __restrict__ npq,
    const float* __restrict__ kraw, const float* __restrict__ npk,
    float* __restrict__ qkout)
{
  __shared__ float s[1000];
  __shared__ float ws2[800];
  const int bid = blockIdx.x;           // 0..4095
  const int xcd = bid & 7;
  const int k = bid >> 3;               // 0..511
  const int tile = xcd * 64 + (k >> 3); // 0..511 (bijective)
  const int j = k & 7;
  const int W0 = (tile & 7) * 8, H0 = ((tile >> 3) & 7) * 8, D0 = (tile >> 6) * 8;
  const int t = threadIdx.x;
  const int cbD = (D0 >> 1) - 1, cbH = (H0 >> 1) - 1, cbW = (W0 >> 1) - 1;
  const float2* npq2 = reinterpret_cast<const float2*>(npq);
  const float2* npk2 = reinterpret_cast<const float2*>(npk);

#pragma unroll
  for (int kk = 0; kk < 7; ++kk) {
    int f = t + kk * 256;
    if (f < 1728) {
      int par = f / 216, idx = f - par * 216;
      int dz = idx / 36, r2 = idx - dz * 36, hz = r2 / 6, wz = r2 - hz * 6;
      int pd = (par >> 2) & 1, ph = (par >> 1) & 1, pw = par & 1;
      int dzf = 2 * dz + pd - 1, hzf = 2 * hz + ph - 1, wzf = 2 * wz + pw - 1;
      if ((unsigned)dzf < 10u && (unsigned)hzf < 10u && (unsigned)wzf < 10u) {
        int cD = cbD + dz, cH = cbH + hz, cW = cbW + wz;
        float prod = 0.f;
        if ((unsigned)cD < 32u && (unsigned)cH < 32u && (unsigned)cW < 32u) {
          int cidx = cD * 1024 + cH * 32 + cW;
          int qc = j * 8 + par;
          float2 nq = npq2[qc];
          float2 nk = npk2[par];
          float qv = fmaxf((qraw[(size_t)qc * VOX + cidx] - nq.x) * nq.y, 0.f);
          float kv = fmaxf((kraw[(size_t)par * VOX + cidx] - nk.x) * nk.y, 0.f);
          prod = qv * kv;
        }
        s[dzf * 100 + hzf * 10 + wzf] = prod;
      }
    }
  }
  __syncthreads();
#pragma unroll
  for (int i = 0; i < 4; ++i) {
    int e = t + i * 256;
    if (e < 800) {
      int dz = e / 80, r2 = e - dz * 80, hz = r2 >> 3, wz1 = r2 & 7;
      int base = dz * 100 + hz * 10 + wz1;
      ws2[e] = s[base] + s[base + 1] + s[base + 2];
    }
  }
  __syncthreads();
#pragma unroll
  for (int rep = 0; rep < 2; ++rep) {
    int o = t + rep * 256;
    int wz = o & 7, hz = (o >> 3) & 7, dz = o >> 6;
    int wb = dz * 80 + hz * 8 + wz;
    float sum = 0.f;
#pragma unroll
    for (int a = 0; a < 3; ++a)
      sum += ws2[wb + a * 80] + ws2[wb + a * 80 + 8] + ws2[wb + a * 80 + 16];
    qkout[(size_t)j * 262144 + (D0 + dz) * 4096 + (H0 + hz) * 64 + (W0 + wz)] =
        sum * (1.f / 27.f);
  }
}

// ---------------------------------------------------------------------------
// einsum_box v10 + XCD swizzle (R21, 120.7us measured).
// ---------------------------------------------------------------------------
__global__ __launch_bounds__(256) void einsum_box_kernel(
    const float* __restrict__ vraw, const float* __restrict__ npv,
    const float* __restrict__ qk, float* __restrict__ out)
{
  __shared__ char vs_raw[2][6912];
  __shared__ float qkvs[1000];
  __shared__ float wsum[800];

  const int bid = blockIdx.x;           // 0..2047
  const int xcd = bid & 7;
  const int k9 = bid >> 3;              // 0..255
  const int tile = xcd * 64 + (k9 >> 2);
  const int sub = k9 & 3;
  const int c0 = (sub & 1) * 32;
  const int ciBase = ((sub >> 1) & 1) * 16;

  const int W0 = (tile & 7) * 8, H0 = ((tile >> 3) & 7) * 8, D0 = (tile >> 6) * 8;
  const int t = threadIdx.x;
  const int cbD = (D0 >> 1) - 1, cbH = (H0 >> 1) - 1, cbW = (W0 >> 1) - 1;
  const float2* npv2 = reinterpret_cast<const float2*>(npv);

  uint soff[7]; int sbyte[7]; int snidx[7]; bool svalid[7];
#pragma unroll
  for (int k = 0; k < 7; ++k) {
    int f = t + k * 256;
    int j = f / 216, idx = f - j * 216;
    int dz = idx / 36, r2 = idx - dz * 36, hz = r2 / 6, wz = r2 - hz * 6;
    int cD = cbD + dz, cH = cbH + hz, cW = cbW + wz;
    bool vld = (f < 1728) && (unsigned)cD < 32u && (unsigned)cH < 32u &&
               (unsigned)cW < 32u;
    svalid[k] = vld;
    soff[k] = vld ? (uint)((c0 * 8 + j) * VOX + cD * 1024 + cH * 32 + cW) : 0u;
    snidx[k] = (f < 1728) ? (c0 * 8 + j) : 0;
    int byte = idx * 32 + (j >> 2) * 16 + (j & 3) * 4;
    sbyte[k] = byte ^ (((idx >> 2) & 7) << 4);
  }

  int vbyte[4]; float qr[4][8];
#pragma unroll
  for (int i = 0; i < 4; ++i) {
    int pos = t + i * 256;
    vbyte[i] = 0;
#pragma unroll
    for (int j = 0; j < 8; ++j) qr[i][j] = 0.f;
    if (pos < 1000) {
      int dz = pos / 100, rem = pos - dz * 100, hz = rem / 10, wz = rem - hz * 10;
      int D = D0 - 1 + dz, H = H0 - 1 + hz, W = W0 - 1 + wz;
      if ((unsigned)D < 64u && (unsigned)H < 64u && (unsigned)W < 64u) {
        int fidx = D * 4096 + H * 64 + W;
#pragma unroll
        for (int j = 0; j < 8; ++j)
          qr[i][j] = qk[(size_t)j * 262144 + fidx];
        int vidx = ((D >> 1) - cbD) * 36 + ((H >> 1) - cbH) * 6 + ((W >> 1) - cbW);
        vbyte[i] = (vidx * 32) ^ (((vidx >> 2) & 7) << 4);
      }
    }
  }

  int wb[4];
#pragma unroll
  for (int i = 0; i < 4; ++i) {
    int e = t + i * 256;
    int dz = e / 80, r2 = e - dz * 80, hz = r2 >> 3, wz1 = r2 & 7;
    wb[i] = dz * 100 + hz * 10 + wz1;
  }
  int wb2[2]; float* op[2];
#pragma unroll
  for (int rep = 0; rep < 2; ++rep) {
    int o = t + rep * 256;
    int wz = o & 7, hz = (o >> 3) & 7, dz = o >> 6;
    wb2[rep] = dz * 80 + hz * 8 + wz;
    op[rep] = out + (size_t)c0 * 262144 +
              (D0 + dz) * 4096 + (H0 + hz) * 64 + (W0 + wz);
  }

  float pre[7];
  auto fetchv = [&](int ci) {
    const uint cio = (uint)(ci * 8 * VOX);
    const int cin8 = ci * 8;
#pragma unroll
    for (int k = 0; k < 7; ++k) {
      if (k < 6 || t < 192) {
        float2 mr = npv2[snidx[k] + cin8];
        float raw = vraw[soff[k] + cio];
        pre[k] = svalid[k] ? fmaxf((raw - mr.x) * mr.y, 0.f) : 0.f;
      }
    }
  };

  fetchv(ciBase);
#pragma unroll
  for (int k = 0; k < 7; ++k)
    if (k < 6 || t < 192)
      *reinterpret_cast<float*>(vs_raw[0] + sbyte[k]) = pre[k];
  fetchv(ciBase + 1);
  __syncthreads();

  for (int li = 0; li < 16; ++li) {
    const int ci = ciBase + li;
    const int cbuf = li & 1;
    if (li < 15) {
#pragma unroll
      for (int k = 0; k < 7; ++k)
        if (k < 6 || t < 192)
          *reinterpret_cast<float*>(vs_raw[cbuf ^ 1] + sbyte[k]) = pre[k];
      if (li < 14) fetchv(ci + 2);
    }
#pragma unroll
    for (int i = 0; i < 4; ++i) {
      int pos = t + i * 256;
      if (pos < 1000) {
        const char* vb0 = vs_raw[cbuf];
        float4 va = *reinterpret_cast<const float4*>(vb0 + vbyte[i]);
        float4 vb = *reinterpret_cast<const float4*>(vb0 + (vbyte[i] ^ 16));
        float val = qr[i][0] * va.x;
        val = fmaf(qr[i][1], va.y, val);
        val = fmaf(qr[i][2], va.z, val);
        val = fmaf(qr[i][3], va.w, val);
        val = fmaf(qr[i][4], vb.x, val);
        val = fmaf(qr[i][5], vb.y, val);
        val = fmaf(qr[i][6], vb.z, val);
        val = fmaf(qr[i][7], vb.w, val);
        qkvs[pos] = val;
      }
    }
    __syncthreads();
#pragma unroll
    for (int i = 0; i < 4; ++i) {
      if (i < 3 || t < 32) {
        int b = wb[i];
        wsum[t + i * 256] = qkvs[b] + qkvs[b + 1] + qkvs[b + 2];
      }
    }
    __syncthreads();
#pragma unroll
    for (int rep = 0; rep < 2; ++rep) {
      float sum = 0.f;
#pragma unroll
      for (int a = 0; a < 3; ++a)
        sum += wsum[wb2[rep] + a * 80] + wsum[wb2[rep] + a * 80 + 8] +
               wsum[wb2[rep] + a * 80 + 16];
      op[rep][(size_t)ci << 18] = sum * (1.f / 27.f);
    }
  }
}

// ---------------------------------------------------------------------------
extern "C" void kernel_launch(void* const* d_in, const int* in_sizes, int n_in,
                              void* d_out, int out_size, void* d_ws, size_t ws_size,
                              hipStream_t stream)
{
  (void)in_sizes; (void)n_in; (void)out_size; (void)ws_size;
  const float* x   = (const float*)d_in[0];
  const float* q1w = (const float*)d_in[1];
  const float* q1b = (const float*)d_in[2];
  const float* q2w = (const float*)d_in[3];
  const float* q2b = (const float*)d_in[4];
  const float* k1w = (const float*)d_in[5];
  const float* k1b = (const float*)d_in[6];
  const float* k2w = (const float*)d_in[7];
  const float* k2b = (const float*)d_in[8];
  const float* vw  = (const float*)d_in[9];
  const float* vb  = (const float*)d_in[10];
  float* out = (float*)d_out;

  float* p = (float*)d_ws;
  float* vraw    = p; p += (size_t)512 * VOX;      // 64 MiB
  float* regionR = p; p += (size_t)96 * VOX;       // 12 MiB: qk1raw then y96
  float* qkbuf   = p; p += (size_t)8 * 262144;     // 8 MiB: xT / xT2 / qk
  float* part_v  = p; p += (size_t)512 * 512 * 2;
  float* part_qk = p; p += (size_t)512 * 32 * 2;
  float* part96  = p; p += (size_t)512 * 96 * 2;
  float* WfF     = p; p += (size_t)262144;
  float* WqF     = p; p += (size_t)16384;
  float* W2F     = p; p += (size_t)49152;
  float* np_qk1  = p; p += 64;
  float* np96    = p; p += 192;
  float* np_v    = p; p += 1024;
  float* bqk     = p; p += 32;
  float* b96     = p; p += 96;
  float* zpadf   = p; p += 4;                      // 16B zero guard

  float* qk1raw = regionR;
  float* y96    = regionR;

  ushort* xT_hi = (ushort*)qkbuf;
  ushort* xT_lo = (ushort*)qkbuf + (size_t)32768 * 64;
  ushort* Wf_hi = (ushort*)WfF;
  ushort* Wf_lo = (ushort*)WfF + 262144;
  ushort* Wq_hi = (ushort*)WqF;
  ushort* Wq_lo = (ushort*)WqF + 16384;
  ushort* W2_hi = (ushort*)W2F;
  ushort* W2_lo = (ushort*)W2F + 49152;
  const ushort* zpad = (const ushort*)zpadf;

  dim3 blk(256);
  prep_all_kernel<<<672, blk, 0, stream>>>(
      x, vw, q1w, q1b, k1w, k1b, q2w, q2b, k2w, k2b,
      xT_hi, xT_lo, Wf_hi, Wf_lo, Wq_hi, Wq_lo, bqk, W2_hi, W2_lo, b96, zpadf);
  conv_fused_kernel<<<768, blk, 0, stream>>>(
      xT_hi, xT_lo, Wf_hi, Wf_lo, vb, vraw, part_v,
      Wq_hi, Wq_lo, bqk, qk1raw, part_qk, zpad);
  finalize3_kernel<<<34, blk, 0, stream>>>(
      part_v, 512, 512, np_v,
      part_qk, 32, 512, np_qk1,
      nullptr, 0, 0, nullptr);
  xprep2_kernel<<<512, blk, 0, stream>>>(qk1raw, np_qk1, xT_hi, xT_lo);
  conv_v_mfma<3, 96><<<dim3(1, 256), blk, 0, stream>>>(
      xT_hi, xT_lo, W2_hi, W2_lo, b96, y96, part96, zpad);
  finalize3_kernel<<<6, blk, 0, stream>>>(
      part96, 96, 512, np96,
      nullptr, 0, 0, nullptr,
      nullptr, 0, 0, nullptr);
  qk_box_kernel<<<4096, blk, 0, stream>>>(
      y96, np96, y96 + (size_t)64 * VOX, np96 + 128, qkbuf);
  einsum_box_kernel<<<2048, blk, 0, stream>>>(
      vraw, np_v, qkbuf, out);
}